// Round 17
// baseline (1093.057 us; speedup 1.0000x reference)
//
#include <hip/hip_runtime.h>

static constexpr int KN  = 256;   // codebook entries
static constexpr int DD  = 384;   // feature dim
static constexpr int DD4 = 96;    // DD/4
static constexpr int TM  = 64;    // rows per block (64x256 block tile)
#define FLAG_MARGIN 0.005f

typedef __attribute__((ext_vector_type(8)))  short bf16x8;   // 8 bf16 = 4 VGPR
typedef __attribute__((ext_vector_type(16))) float f32x16;   // MFMA 32x32 acc

__device__ __forceinline__ unsigned short f2bf_rne(float x) {
  unsigned u = __float_as_uint(x);
  return (unsigned short)((u + 0x7fffu + ((u >> 16) & 1u)) >> 16);
}

// async global->LDS, 16B per lane (dest = wave-uniform base + lane*16)
__device__ __forceinline__ void g2lds16(const void* g, void* l) {
  __builtin_amdgcn_global_load_lds(
      (const __attribute__((address_space(1))) unsigned int*)g,
      (__attribute__((address_space(3))) unsigned int*)l, 16, 0, 0);
}

// ======== numpy-fp32 emulation helpers (VALIDATED round 4 — do not touch) ====
__device__ __forceinline__ float emu_sq_pairwise384(const float* __restrict__ p) {
  float S[4];
#pragma unroll
  for (int blk = 0; blk < 4; ++blk) {
    const float* b = p + blk * 96;
    float r[8];
#pragma unroll
    for (int l = 0; l < 8; ++l) r[l] = __fmul_rn(b[l], b[l]);
    for (int j = 8; j < 96; j += 8) {
#pragma unroll
      for (int l = 0; l < 8; ++l) r[l] = __fadd_rn(r[l], __fmul_rn(b[j + l], b[j + l]));
    }
    float t1 = __fadd_rn(__fadd_rn(r[0], r[1]), __fadd_rn(r[2], r[3]));
    float t2 = __fadd_rn(__fadd_rn(r[4], r[5]), __fadd_rn(r[6], r[7]));
    S[blk] = __fadd_rn(t1, t2);
  }
  return __fadd_rn(__fadd_rn(S[0], S[1]), __fadd_rn(S[2], S[3]));
}

__device__ __forceinline__ float emu_dot384_np(const float* __restrict__ x,
                                               const float* __restrict__ c) {
  float s[16];
#pragma unroll
  for (int t = 0; t < 16; ++t) s[t] = 0.f;
  for (int j = 0; j < 384; j += 16) {
#pragma unroll
    for (int t = 0; t < 16; ++t)
      s[t] = __fadd_rn(__fmul_rn(x[j + t], c[j + t]), s[t]);
  }
  float w0 = __fadd_rn(__fadd_rn(s[0], s[4]), __fadd_rn(s[8],  s[12]));
  float w1 = __fadd_rn(__fadd_rn(s[1], s[5]), __fadd_rn(s[9],  s[13]));
  float w2 = __fadd_rn(__fadd_rn(s[2], s[6]), __fadd_rn(s[10], s[14]));
  float w3 = __fadd_rn(__fadd_rn(s[3], s[7]), __fadd_rn(s[11], s[15]));
  return __fadd_rn(__fadd_rn(w0, w1), __fadd_rn(w2, w3));
}

// ---------------- prep: codebook norms (3 blocks) + bf16-split (144 blocks) --
__global__ __launch_bounds__(256) void prep_kernel(const float* __restrict__ c0,
                                                   const float* __restrict__ c1,
                                                   const float* __restrict__ c2,
                                                   float* __restrict__ e2,
                                                   double* __restrict__ delta,
                                                   short* __restrict__ fragbase) {
  int bid = blockIdx.x;
  if (bid < 3) {
    const float* cb = (bid == 0) ? c0 : ((bid == 1) ? c1 : c2);
    e2[bid * KN + threadIdx.x] = emu_sq_pairwise384(cb + (size_t)threadIdx.x * DD);
    if (threadIdx.x == 0) delta[bid] = 0.0;
    return;
  }
  int sb = bid - 3;                 // 0..143
  int lvl = sb / 48;
  int blk48 = sb - lvl * 48;
  const float* cb = (lvl == 0) ? c0 : ((lvl == 1) ? c1 : c2);
  short* frag = fragbase + (size_t)lvl * 196608;
  int gid = blk48 * 256 + threadIdx.x;            // 12288 = 256 entries * 48 groups
  int e = gid / 48;
  int g = gid - e * 48;
  const float4* s4 = reinterpret_cast<const float4*>(cb) + (size_t)e * 96 + g * 2;
  float4 v0 = s4[0], v1 = s4[1];
  float xs[8] = {v0.x, v0.y, v0.z, v0.w, v1.x, v1.y, v1.z, v1.w};
  short h[8], l[8];
#pragma unroll
  for (int i = 0; i < 8; ++i) {
    h[i] = (short)f2bf_rne(xs[i]);
    float hf = __uint_as_float((unsigned)(unsigned short)h[i] << 16);
    l[i] = (short)f2bf_rne(xs[i] - hf);
  }
  int c = g >> 2, rem = g & 3, ks = rem >> 1, hs = rem & 1;
  int t = e >> 5, lane = (e & 31) + (hs << 5);
  size_t blk = (((size_t)(c * 8 + t) * 2 + ks) * 2);
  short* dh = frag + blk * 512 + lane * 8;
  short* dl = dh + 512;
  *reinterpret_cast<bf16x8*>(dh) = *reinterpret_cast<const bf16x8*>(h);
  *reinterpret_cast<bf16x8*>(dl) = *reinterpret_cast<const bf16x8*>(l);
}

// ---------------- phase 1: merged 3-level MFMA GEMM, 1-barrier dbuf ---------
// 512 threads = 8 waves; wave wid owns 64 rows x cols [wid*32,+32) as 2 tiles
// -> acc[2] = 32 AGPR. 24 chunks of K=16. SINGLE barrier per chunk: stage(c+1)
// issued BEFORE compute(c) (T3 2-phase); CB+X double-buffered (40KB total ->
// 4 blocks/CU); X prefetched 2 chunks ahead into rotating regs (static parity
// via unroll-by-2). Rounds 12-16 showed the serial stage->drain->compute
// structure leaves every pipe <40% busy regardless of occupancy.
__global__ __launch_bounds__(512) void vq_main(
    const float* __restrict__ X0, const float* __restrict__ X1, const float* __restrict__ X2,
    const float* __restrict__ C0, const float* __restrict__ C1, const float* __restrict__ C2,
    const short* __restrict__ FRAGBASE,
    const float* __restrict__ E2A,
    float* __restrict__ QBASE,
    float* __restrict__ IDXBASE,
    unsigned char* __restrict__ FLAGBASE,
    double* __restrict__ PART,
    int nb0, int nb1)
{
  __shared__ __align__(16) short cb_lds[2][8192];  // 2 x 16KB: [t(8)][hl(2)] 1KB
  __shared__ __align__(16) short x_lds[2][2048];   // 2 x 4KB:  [rt(2)][hl(2)] 1KB
  // epilogue overlay on cb_lds[0] (live only after the K loop; 6.5KB <= 16KB)
  struct Epi {
    float b1[8][TM]; int i1[8][TM]; float b2[8][TM];
    int idx[TM]; float xx[TM];
  };
  Epi* ep = reinterpret_cast<Epi*>(&cb_lds[0][0]);

  const int bid = blockIdx.x;
  int lvl, lb;
  if (bid < nb0)            { lvl = 0; lb = bid; }
  else if (bid < nb0 + nb1) { lvl = 1; lb = bid - nb0; }
  else                      { lvl = 2; lb = bid - nb0 - nb1; }
  const float* X  = (lvl == 0) ? X0 : ((lvl == 1) ? X1 : X2);
  const float* CBF32 = (lvl == 0) ? C0 : ((lvl == 1) ? C1 : C2);
  const short* CBFRAG = FRAGBASE + (size_t)lvl * 196608;
  const float* E2 = E2A + lvl * KN;
  const size_t rowbase = (lvl == 0) ? 0 : ((lvl == 1) ? (size_t)nb0 * TM
                                                      : (size_t)(nb0 + nb1) * TM);
  float* Q = QBASE + rowbase * DD;
  float* IDXO = IDXBASE + rowbase;
  unsigned char* FLAG = FLAGBASE + rowbase;
  const size_t row0 = (size_t)lb * TM;

  const int tid  = threadIdx.x;            // 0..511
  const int wid  = tid >> 6, lane = tid & 63;
  const int lr   = lane & 31, hi = lane >> 5;
  const int r_st = tid >> 3, k2 = tid & 7; // staging: row (0..63), float2 slot

  const float2* xsrc2 = reinterpret_cast<const float2*>(X)
                        + (row0 + (size_t)r_st) * 192 + k2;

  f32x16 acc[2];
  {
    f32x16 z;
#pragma unroll
    for (int i = 0; i < 16; ++i) z[i] = 0.f;
    acc[0] = z; acc[1] = z;
  }
  float xx = 0.f;

  // X write position: rt = r_st>>5, lane_x = (r_st&31)+32*(k2>=4)
  const int xblk2 = (r_st >> 5) * 2;                              // h block index
  const int xpos  = (((k2 >> 2) * 32 + (r_st & 31)) * 16) + (k2 & 3) * 4;

#define STAGE_CB(CN)                                                          \
  {                                                                           \
    const int par_ = (CN) & 1;                                                \
    _Pragma("unroll")                                                         \
    for (int s = 0; s < 2; ++s) {                                             \
      int idx = s * 512 + tid;            /* 0..1023 */                       \
      int b = idx >> 6;                   /* 0..15: t=b>>1, hl=b&1 */         \
      const char* src = (const char*)CBFRAG                                   \
          + ((((size_t)((CN) >> 1) * 8 + (b >> 1)) * 4 + ((CN) & 1) * 2       \
              + (b & 1)) << 10) + (idx & 63) * 16;                            \
      g2lds16(src, (char*)cb_lds[par_] + idx * 16);                           \
    }                                                                         \
  }

#define CVT_WRITE_X(CN, XF)                                                   \
  {                                                                           \
    float a0_ = (XF).x, a1_ = (XF).y;                                         \
    xx = fmaf(a0_, a0_, xx); xx = fmaf(a1_, a1_, xx);                         \
    unsigned u0_ = __float_as_uint(a0_);                                      \
    unsigned t0_ = u0_ + 0x7fffu + ((u0_ >> 16) & 1u);                        \
    unsigned u1_ = __float_as_uint(a1_);                                      \
    unsigned t1_ = u1_ + 0x7fffu + ((u1_ >> 16) & 1u);                        \
    unsigned hp_ = (t0_ >> 16) | (t1_ & 0xffff0000u);                         \
    float l0_ = a0_ - __uint_as_float(t0_ & 0xffff0000u);                     \
    float l1_ = a1_ - __uint_as_float(t1_ & 0xffff0000u);                     \
    unsigned lp_ = (__float_as_uint(l0_) >> 16)                               \
                   | (__float_as_uint(l1_) & 0xffff0000u);                    \
    char* xb_ = (char*)x_lds[(CN) & 1];                                       \
    *reinterpret_cast<unsigned*>(xb_ + xblk2 * 1024 + xpos)        = hp_;     \
    *reinterpret_cast<unsigned*>(xb_ + (xblk2 + 1) * 1024 + xpos)  = lp_;     \
  }

#define MFMA_PHASE(CN)                                                        \
  {                                                                           \
    const char* xb_ = (const char*)x_lds[(CN) & 1];                           \
    bf16x8 ah0 = *reinterpret_cast<const bf16x8*>(xb_ +        lane * 16);    \
    bf16x8 al0 = *reinterpret_cast<const bf16x8*>(xb_ + 1024 + lane * 16);    \
    bf16x8 ah1 = *reinterpret_cast<const bf16x8*>(xb_ + 2048 + lane * 16);    \
    bf16x8 al1 = *reinterpret_cast<const bf16x8*>(xb_ + 3072 + lane * 16);    \
    const char* bb_ = (const char*)cb_lds[(CN) & 1];                          \
    bf16x8 bh = *reinterpret_cast<const bf16x8*>(bb_ + (wid * 2 + 0) * 1024   \
                                                 + lane * 16);                \
    bf16x8 bl = *reinterpret_cast<const bf16x8*>(bb_ + (wid * 2 + 1) * 1024   \
                                                 + lane * 16);                \
    acc[0] = __builtin_amdgcn_mfma_f32_32x32x16_bf16(ah0, bh, acc[0], 0, 0, 0);\
    acc[0] = __builtin_amdgcn_mfma_f32_32x32x16_bf16(ah0, bl, acc[0], 0, 0, 0);\
    acc[0] = __builtin_amdgcn_mfma_f32_32x32x16_bf16(al0, bh, acc[0], 0, 0, 0);\
    acc[1] = __builtin_amdgcn_mfma_f32_32x32x16_bf16(ah1, bh, acc[1], 0, 0, 0);\
    acc[1] = __builtin_amdgcn_mfma_f32_32x32x16_bf16(ah1, bl, acc[1], 0, 0, 0);\
    acc[1] = __builtin_amdgcn_mfma_f32_32x32x16_bf16(al1, bh, acc[1], 0, 0, 0);\
  }

  // ---- prologue: stage chunk 0, prefetch X(1) ----
  float2 xfA = xsrc2[0];
  float2 xfB;
  STAGE_CB(0);
  CVT_WRITE_X(0, xfA);
  xfA = xsrc2[8];            // X(1)
  __syncthreads();

#pragma unroll 1
  for (int cc = 0; cc < 12; ++cc) {
    const int c0 = 2 * cc, c1 = 2 * cc + 1;
    // --- body A: compute chunk c0 (buf0); stage c0+1 (buf1) ---
    STAGE_CB(c0 + 1);
    if (c0 < 22) xfB = xsrc2[(c0 + 2) * 8];
    MFMA_PHASE(c0);
    CVT_WRITE_X(c0 + 1, xfA);
    __syncthreads();
    // --- body B: compute chunk c1 (buf1); stage c1+1 (buf0) ---
    if (c1 < 23) {
      STAGE_CB(c1 + 1);
      if (c1 < 22) xfA = xsrc2[(c1 + 2) * 8];
      MFMA_PHASE(c1);
      CVT_WRITE_X(c1 + 1, xfB);
    } else {
      MFMA_PHASE(23);
    }
    __syncthreads();
  }

  // ---- row norms: reduce the 8-thread k2 group -> overlay ----
  {
    float t = xx;
    t += __shfl_xor(t, 1);
    t += __shfl_xor(t, 2);
    t += __shfl_xor(t, 4);
    if ((tid & 7) == 0) ep->xx[r_st] = t;
  }

  // ---- argmin epilogue: D layout col=lane&31, row=(v&3)+8*(v>>2)+4*hi ----
  const float e2v = E2[wid * 32 + lr];
  const int mycol = wid * 32 + lr;

#pragma unroll
  for (int rt = 0; rt < 2; ++rt) {
#pragma unroll
    for (int v = 0; v < 16; ++v) {
      int row = rt * 32 + (v & 3) + 8 * (v >> 2) + 4 * hi;
      float sc = e2v - 2.0f * acc[rt][v];
      float b1 = sc; int i1 = mycol;
#pragma unroll
      for (int m = 1; m < 32; m <<= 1) {   // within 32-lane halves (hi preserved)
        float ob = __shfl_xor(b1, m);
        int   oi = __shfl_xor(i1, m);
        if (ob < b1 || (ob == b1 && oi < i1)) { b1 = ob; i1 = oi; }
      }
      float b2 = (mycol != i1) ? sc : 1e30f;
#pragma unroll
      for (int m = 1; m < 32; m <<= 1) {
        float ob = __shfl_xor(b2, m);
        if (ob < b2) b2 = ob;
      }
      if (lr == 0) {
        ep->b1[wid][row] = b1; ep->i1[wid][row] = i1; ep->b2[wid][row] = b2;
      }
    }
  }
  __syncthreads();

  // merge 8 waves' candidates; idx/flag; per-row loss = xx + b1
  double lrow = 0.0;
  if (tid < TM) {
    float b1 = ep->b1[0][tid]; int i1 = ep->i1[0][tid]; float b2 = ep->b2[0][tid];
#pragma unroll
    for (int w = 1; w < 8; ++w) {
      float ob1 = ep->b1[w][tid]; int oi1 = ep->i1[w][tid]; float ob2 = ep->b2[w][tid];
      if (ob1 < b1 || (ob1 == b1 && oi1 < i1)) {
        b2 = fminf(b1, ob2); b1 = ob1; i1 = oi1;
      } else {
        b2 = fminf(b2, ob1);
      }
    }
    ep->idx[tid] = i1;
    IDXO[row0 + tid] = (float)i1;
    FLAG[row0 + tid] = (b2 - b1 < FLAG_MARGIN) ? 1 : 0;
    lrow = (double)ep->xx[tid] + (double)b1;
  }
  if (tid < 64) {
#pragma unroll
    for (int m = 1; m < 64; m <<= 1) lrow += __shfl_xor(lrow, m);
    if (tid == 0) PART[bid] = lrow;
  }
  __syncthreads();

  // ---- output: q = cb[idx] (pure gather+write; no X re-read) ----
  const float4* CB4 = reinterpret_cast<const float4*>(CBF32);
  float4* Q4 = reinterpret_cast<float4*>(Q);
  for (int i = tid; i < TM * DD4; i += 512) {
    int r = i / DD4;
    int cc = i - r * DD4;
    Q4[(row0 + (size_t)r) * DD4 + cc] = CB4[(size_t)ep->idx[r] * DD4 + cc];
  }
}

// ---------------- phase 2: numpy-exact refine, all 3 levels, one launch -----
__global__ __launch_bounds__(256) void vq_refine(
    const float* __restrict__ X0, const float* __restrict__ X1, const float* __restrict__ X2,
    const float* __restrict__ C0, const float* __restrict__ C1, const float* __restrict__ C2,
    const float* __restrict__ E2A,
    const unsigned char* __restrict__ F0, const unsigned char* __restrict__ F1,
    const unsigned char* __restrict__ F2,
    int r0, int r1, int r2,
    float* __restrict__ Q0, float* __restrict__ Q1, float* __restrict__ Q2,
    float* __restrict__ I0, float* __restrict__ I1, float* __restrict__ I2,
    double* __restrict__ DELTA)
{
  const int lane   = threadIdx.x & 63;
  const int gwave  = (blockIdx.x * blockDim.x + threadIdx.x) >> 6;
  const int nwaves = (gridDim.x * blockDim.x) >> 6;
  const int ntot = r0 + r1 + r2;

  for (int base = gwave * 64; base < ntot; base += nwaves * 64) {
    int lvl, lb;
    const float *X, *CB; const unsigned char* FLAG; float *Q, *IDXO;
    if (base < r0)           { lvl = 0; lb = base;            X = X0; CB = C0; FLAG = F0; Q = Q0; IDXO = I0; }
    else if (base < r0 + r1) { lvl = 1; lb = base - r0;       X = X1; CB = C1; FLAG = F1; Q = Q1; IDXO = I1; }
    else                     { lvl = 2; lb = base - r0 - r1;  X = X2; CB = C2; FLAG = F2; Q = Q2; IDXO = I2; }
    const float* E2EMU = E2A + lvl * KN;

    unsigned char f = FLAG[lb + lane];
    unsigned long long mask = __ballot(f != 0);
    while (mask) {
      int bit = __ffsll((long long)mask) - 1;
      mask &= mask - 1;
      const int r = lb + bit;
      const float* xr = X + (size_t)r * DD;
      const float xx = emu_sq_pairwise384(xr);

      float best = 1e30f; int bidx = 0x7fffffff;
#pragma unroll
      for (int t = 0; t < 4; ++t) {
        int k = lane * 4 + t;
        const float* ck = CB + (size_t)k * DD;
        float E = emu_dot384_np(xr, ck);
        float s = __fadd_rn(__fsub_rn(xx, __fmul_rn(2.0f, E)), E2EMU[k]);
        if (s < best || (s == best && k < bidx)) { best = s; bidx = k; }
      }
#pragma unroll
      for (int m = 1; m < 64; m <<= 1) {
        float ob = __shfl_xor(best, m);
        int   oi = __shfl_xor(bidx, m);
        if (ob < best || (ob == best && oi < bidx)) { best = ob; bidx = oi; }
      }

      const int old = (int)IDXO[r];
      if (bidx != old) {
        const float* cn = CB + (size_t)bidx * DD;
        const float* co = CB + (size_t)old * DD;
        double dl = 0.0;
        for (int d = lane; d < DD; d += 64) {
          float xv = xr[d];
          float qn = cn[d], qo = co[d];
          Q[(size_t)r * DD + d] = qn;
          double en = (double)qn - (double)xv;
          double eo = (double)qo - (double)xv;
          dl += en * en - eo * eo;
        }
#pragma unroll
        for (int m = 1; m < 64; m <<= 1) dl += __shfl_xor(dl, m);
        if (lane == 0) {
          atomicAdd(DELTA + lvl, dl);
          IDXO[r] = (float)bidx;
        }
      }
    }
  }
}

// ---------------- loss finalize ----------------
__global__ void finalize_kernel(const double* __restrict__ p0, int n0, double w0,
                                const double* __restrict__ p1, int n1, double w1,
                                const double* __restrict__ p2, int n2, double w2,
                                const double* __restrict__ delta,
                                float* __restrict__ out) {
  __shared__ double red[4];
  int tid = threadIdx.x;
  double s0 = 0.0, s1 = 0.0, s2 = 0.0;
  for (int i = tid; i < n0; i += 256) s0 += p0[i];
  for (int i = tid; i < n1; i += 256) s1 += p1[i];
  for (int i = tid; i < n2; i += 256) s2 += p2[i];
  double v = s0 * w0 + s1 * w1 + s2 * w2;
#pragma unroll
  for (int m = 1; m < 64; m <<= 1) v += __shfl_xor(v, m);
  if ((tid & 63) == 0) red[tid >> 6] = v;
  __syncthreads();
  if (tid == 0)
    out[0] = (float)(red[0] + red[1] + red[2] + red[3]
                     + delta[0] * w0 + delta[1] * w1 + delta[2] * w2);
}

extern "C" void kernel_launch(void* const* d_in, const int* in_sizes, int n_in,
                              void* d_out, int out_size, void* d_ws, size_t ws_size,
                              hipStream_t stream) {
  const float* l0  = (const float*)d_in[0];
  const float* l1  = (const float*)d_in[1];
  const float* l2  = (const float*)d_in[2];
  const float* cb0 = (const float*)d_in[3];
  const float* cb1 = (const float*)d_in[4];
  const float* cb2 = (const float*)d_in[5];

  const size_t n_q0 = (size_t)in_sizes[0];
  const size_t n_q1 = (size_t)in_sizes[1];
  const size_t n_q2 = (size_t)in_sizes[2];
  const int r0 = (int)(n_q0 / DD);   // 65536
  const int r1 = (int)(n_q1 / DD);   // 262144
  const int r2 = (int)(n_q2 / DD);   // 262144

  float* out   = (float*)d_out;
  float* q0    = out;
  float* q1    = q0 + n_q0;
  float* q2    = q1 + n_q1;
  float* lossp = q2 + n_q2;
  float* idx0  = lossp + 1;
  float* idx1  = idx0 + r0;
  float* idx2  = idx1 + r1;

  // ws layout
  float*  e2    = (float*)d_ws;                          // 3*256 f32
  double* part  = (double*)((char*)d_ws + 4096);         // 9216 doubles
  double* delta = (double*)((char*)d_ws + 4096 + 73728);
  unsigned char* flag0 = (unsigned char*)d_ws + 4096 + 73728 + 1024;
  unsigned char* flag1 = flag0 + r0;
  unsigned char* flag2 = flag1 + r1;
  short* cbf0 = (short*)((char*)d_ws + (1 << 20));       // 3 x 384 KiB

  const int nb0 = r0 / TM, nb1 = r1 / TM, nb2 = r2 / TM;  // 1024/4096/4096
  double* p0 = part;
  double* p1 = p0 + nb0;
  double* p2 = p1 + nb1;

  prep_kernel<<<147, 256, 0, stream>>>(cb0, cb1, cb2, e2, delta, cbf0);

  vq_main<<<nb0 + nb1 + nb2, 512, 0, stream>>>(
      l0, l1, l2, cb0, cb1, cb2, cbf0, e2,
      q0, idx0, flag0, part, nb0, nb1);

  vq_refine<<<512, 256, 0, stream>>>(l0, l1, l2, cb0, cb1, cb2, e2,
                                     flag0, flag1, flag2, r0, r1, r2,
                                     q0, q1, q2, idx0, idx1, idx2, delta);

  const double w0 = 0.05 / ((double)r0 * DD);
  const double w1 = 0.25 / ((double)r1 * DD);
  const double w2 = 0.60 / ((double)r2 * DD);
  finalize_kernel<<<1, 256, 0, stream>>>(p0, nb0, w0, p1, nb1, w1, p2, nb2, w2,
                                         delta, lossp);
}

// Round 18
// 1006.961 us; speedup vs baseline: 1.0855x; 1.0855x over previous
//
#include <hip/hip_runtime.h>

static constexpr int KN  = 256;   // codebook entries
static constexpr int DD  = 384;   // feature dim
static constexpr int DD4 = 96;    // DD/4
static constexpr int TM  = 64;    // rows per block (64x256 block tile)
#define FLAG_MARGIN 0.005f

typedef __attribute__((ext_vector_type(8)))  short bf16x8;   // 8 bf16 = 4 VGPR
typedef __attribute__((ext_vector_type(16))) float f32x16;   // MFMA 32x32 acc

__device__ __forceinline__ unsigned short f2bf_rne(float x) {
  unsigned u = __float_as_uint(x);
  return (unsigned short)((u + 0x7fffu + ((u >> 16) & 1u)) >> 16);
}

// async global->LDS, 16B per lane (dest = wave-uniform base + lane*16)
__device__ __forceinline__ void g2lds16(const void* g, void* l) {
  __builtin_amdgcn_global_load_lds(
      (const __attribute__((address_space(1))) unsigned int*)g,
      (__attribute__((address_space(3))) unsigned int*)l, 16, 0, 0);
}

// fp32x8 (two float4) -> bf16 high/low split + xx accumulation
__device__ __forceinline__ void cvt8(float4 a, float4 b, bf16x8& h, bf16x8& l,
                                     float& xx) {
  float v[8] = {a.x, a.y, a.z, a.w, b.x, b.y, b.z, b.w};
#pragma unroll
  for (int i = 0; i < 8; ++i) {
    xx = fmaf(v[i], v[i], xx);
    unsigned short hh = f2bf_rne(v[i]);
    float hf = __uint_as_float((unsigned)hh << 16);
    h[i] = (short)hh;
    l[i] = (short)f2bf_rne(v[i] - hf);
  }
}

// ======== numpy-fp32 emulation helpers (VALIDATED round 4 — do not touch) ====
__device__ __forceinline__ float emu_sq_pairwise384(const float* __restrict__ p) {
  float S[4];
#pragma unroll
  for (int blk = 0; blk < 4; ++blk) {
    const float* b = p + blk * 96;
    float r[8];
#pragma unroll
    for (int l = 0; l < 8; ++l) r[l] = __fmul_rn(b[l], b[l]);
    for (int j = 8; j < 96; j += 8) {
#pragma unroll
      for (int l = 0; l < 8; ++l) r[l] = __fadd_rn(r[l], __fmul_rn(b[j + l], b[j + l]));
    }
    float t1 = __fadd_rn(__fadd_rn(r[0], r[1]), __fadd_rn(r[2], r[3]));
    float t2 = __fadd_rn(__fadd_rn(r[4], r[5]), __fadd_rn(r[6], r[7]));
    S[blk] = __fadd_rn(t1, t2);
  }
  return __fadd_rn(__fadd_rn(S[0], S[1]), __fadd_rn(S[2], S[3]));
}

__device__ __forceinline__ float emu_dot384_np(const float* __restrict__ x,
                                               const float* __restrict__ c) {
  float s[16];
#pragma unroll
  for (int t = 0; t < 16; ++t) s[t] = 0.f;
  for (int j = 0; j < 384; j += 16) {
#pragma unroll
    for (int t = 0; t < 16; ++t)
      s[t] = __fadd_rn(__fmul_rn(x[j + t], c[j + t]), s[t]);
  }
  float w0 = __fadd_rn(__fadd_rn(s[0], s[4]), __fadd_rn(s[8],  s[12]));
  float w1 = __fadd_rn(__fadd_rn(s[1], s[5]), __fadd_rn(s[9],  s[13]));
  float w2 = __fadd_rn(__fadd_rn(s[2], s[6]), __fadd_rn(s[10], s[14]));
  float w3 = __fadd_rn(__fadd_rn(s[3], s[7]), __fadd_rn(s[11], s[15]));
  return __fadd_rn(__fadd_rn(w0, w1), __fadd_rn(w2, w3));
}

// ---------------- prep: codebook norms (3 blocks) + bf16-split (144 blocks) --
__global__ __launch_bounds__(256) void prep_kernel(const float* __restrict__ c0,
                                                   const float* __restrict__ c1,
                                                   const float* __restrict__ c2,
                                                   float* __restrict__ e2,
                                                   double* __restrict__ delta,
                                                   short* __restrict__ fragbase) {
  int bid = blockIdx.x;
  if (bid < 3) {
    const float* cb = (bid == 0) ? c0 : ((bid == 1) ? c1 : c2);
    e2[bid * KN + threadIdx.x] = emu_sq_pairwise384(cb + (size_t)threadIdx.x * DD);
    if (threadIdx.x == 0) delta[bid] = 0.0;
    return;
  }
  int sb = bid - 3;                 // 0..143
  int lvl = sb / 48;
  int blk48 = sb - lvl * 48;
  const float* cb = (lvl == 0) ? c0 : ((lvl == 1) ? c1 : c2);
  short* frag = fragbase + (size_t)lvl * 196608;
  int gid = blk48 * 256 + threadIdx.x;            // 12288 = 256 entries * 48 groups
  int e = gid / 48;
  int g = gid - e * 48;
  const float4* s4 = reinterpret_cast<const float4*>(cb) + (size_t)e * 96 + g * 2;
  float4 v0 = s4[0], v1 = s4[1];
  float xs[8] = {v0.x, v0.y, v0.z, v0.w, v1.x, v1.y, v1.z, v1.w};
  short h[8], l[8];
#pragma unroll
  for (int i = 0; i < 8; ++i) {
    h[i] = (short)f2bf_rne(xs[i]);
    float hf = __uint_as_float((unsigned)(unsigned short)h[i] << 16);
    l[i] = (short)f2bf_rne(xs[i] - hf);
  }
  int c = g >> 2, rem = g & 3, ks = rem >> 1, hs = rem & 1;
  int t = e >> 5, lane = (e & 31) + (hs << 5);
  size_t blk = (((size_t)(c * 8 + t) * 2 + ks) * 2);
  short* dh = frag + blk * 512 + lane * 8;
  short* dl = dh + 512;
  *reinterpret_cast<bf16x8*>(dh) = *reinterpret_cast<const bf16x8*>(h);
  *reinterpret_cast<bf16x8*>(dl) = *reinterpret_cast<const bf16x8*>(l);
}

// ---------------- phase 1: merged 3-level MFMA GEMM, reg-A / LDS-B ----------
// r12's proven skeleton (256 thr, 4 waves 2x2, acc[4], single 32KB CB buffer,
// stage->sync->MFMA->sync) with the X-LDS round-trip DELETED: each lane's
// A-fragment is 8 contiguous elements of its own row -> global->reg->convert,
// prefetched one chunk ahead (issued before barrier-1, consumed after). Kills
// the serial store-chain + the 7M x_lds bank conflicts that capped r12-r17.
__global__ __launch_bounds__(256) void vq_main(
    const float* __restrict__ X0, const float* __restrict__ X1, const float* __restrict__ X2,
    const float* __restrict__ C0, const float* __restrict__ C1, const float* __restrict__ C2,
    const short* __restrict__ FRAGBASE,
    const float* __restrict__ E2A,
    float* __restrict__ QBASE,
    float* __restrict__ IDXBASE,
    unsigned char* __restrict__ FLAGBASE,
    double* __restrict__ PART,
    int nb0, int nb1)
{
  __shared__ __align__(16) short cb_lds[16384];  // 32KB: [t(8)][ks(2)][hl(2)] 1KB
  // epilogue overlay on cb_lds (live only after the K loop; ~2KB)
  struct Epi {
    float b1[2][TM]; int i1[2][TM]; float b2[2][TM];
    int idx[TM]; float xx[TM];
  };
  Epi* ep = reinterpret_cast<Epi*>(cb_lds);

  const int bid = blockIdx.x;
  int lvl, lb;
  if (bid < nb0)            { lvl = 0; lb = bid; }
  else if (bid < nb0 + nb1) { lvl = 1; lb = bid - nb0; }
  else                      { lvl = 2; lb = bid - nb0 - nb1; }
  const float* X  = (lvl == 0) ? X0 : ((lvl == 1) ? X1 : X2);
  const float* CBF32 = (lvl == 0) ? C0 : ((lvl == 1) ? C1 : C2);
  const short* CBFRAG = FRAGBASE + (size_t)lvl * 196608;
  const float* E2 = E2A + lvl * KN;
  const size_t rowbase = (lvl == 0) ? 0 : ((lvl == 1) ? (size_t)nb0 * TM
                                                      : (size_t)(nb0 + nb1) * TM);
  float* Q = QBASE + rowbase * DD;
  float* IDXO = IDXBASE + rowbase;
  unsigned char* FLAG = FLAGBASE + rowbase;
  const size_t row0 = (size_t)lb * TM;

  const int tid  = threadIdx.x;
  const int wid  = tid >> 6, lane = tid & 63;
  const int lr   = lane & 31, hi = lane >> 5;
  const int wr   = wid >> 1, wc = wid & 1;

  const float4* X4 = reinterpret_cast<const float4*>(X);
  // this lane's A-fragment source: row = row0+wr*32+lr, k-half hi
  const float4* xrow = X4 + (row0 + (size_t)(wr * 32 + lr)) * DD4 + hi * 2;

  f32x16 acc[4];
  {
    f32x16 z;
#pragma unroll
    for (int i = 0; i < 16; ++i) z[i] = 0.f;
#pragma unroll
    for (int ct = 0; ct < 4; ++ct) acc[ct] = z;
  }
  float xx = 0.f;

  // prologue: X(0) -> regs
  float4 x0 = xrow[0], x1 = xrow[1], x2 = xrow[4], x3 = xrow[5];

#pragma unroll 1
  for (int c = 0; c < 12; ++c) {
    // ---- stage CB chunk c (async, single buffer) ----
#pragma unroll
    for (int s = 0; s < 8; ++s) {
      int idx = s * 256 + tid;
      g2lds16((const char*)CBFRAG + (size_t)c * 32768 + idx * 16,
              (char*)cb_lds + idx * 16);
    }
    // ---- prefetch X(c+1) -> regs (drains at barrier; hidden by MFMA) ----
    float4 n0, n1, n2, n3;
    if (c < 11) {
      const float4* xp = xrow + (c + 1) * 8;
      n0 = xp[0]; n1 = xp[1]; n2 = xp[4]; n3 = xp[5];
    }
    // ---- convert current X (resident since last iteration) ----
    bf16x8 ah0, al0, ah1, al1;
    cvt8(x0, x1, ah0, al0, xx);   // ks=0
    cvt8(x2, x3, ah1, al1, xx);   // ks=1
    __syncthreads();              // CB ready; X(c+1) drained too

    // ---- MFMA phase: A from regs, B from LDS (lane-linear, conflict-free) --
    const bf16x8* bb = reinterpret_cast<const bf16x8*>(cb_lds);
#pragma unroll
    for (int ct = 0; ct < 4; ++ct) {
      int t = wc * 4 + ct;
      bf16x8 bh0 = bb[((t * 2 + 0) * 2 + 0) * 64 + lane];
      bf16x8 bl0 = bb[((t * 2 + 0) * 2 + 1) * 64 + lane];
      bf16x8 bh1 = bb[((t * 2 + 1) * 2 + 0) * 64 + lane];
      bf16x8 bl1 = bb[((t * 2 + 1) * 2 + 1) * 64 + lane];
      acc[ct] = __builtin_amdgcn_mfma_f32_32x32x16_bf16(ah0, bh0, acc[ct], 0, 0, 0);
      acc[ct] = __builtin_amdgcn_mfma_f32_32x32x16_bf16(ah0, bl0, acc[ct], 0, 0, 0);
      acc[ct] = __builtin_amdgcn_mfma_f32_32x32x16_bf16(al0, bh0, acc[ct], 0, 0, 0);
      acc[ct] = __builtin_amdgcn_mfma_f32_32x32x16_bf16(ah1, bh1, acc[ct], 0, 0, 0);
      acc[ct] = __builtin_amdgcn_mfma_f32_32x32x16_bf16(ah1, bl1, acc[ct], 0, 0, 0);
      acc[ct] = __builtin_amdgcn_mfma_f32_32x32x16_bf16(al1, bh1, acc[ct], 0, 0, 0);
    }
    __syncthreads();              // protect cb_lds before next stage
    if (c < 11) { x0 = n0; x1 = n1; x2 = n2; x3 = n3; }
  }

  // ---- row norms: lane + partner(lane^32) cover the full row ----
  xx += __shfl_xor(xx, 32);
  if (wc == 0 && hi == 0) ep->xx[wr * 32 + lr] = xx;

  // ---- argmin epilogue: D layout col=lane&31, row=(v&3)+8*(v>>2)+4*hi ----
  float e2v[4];
#pragma unroll
  for (int ct = 0; ct < 4; ++ct) e2v[ct] = E2[wc * 128 + ct * 32 + lr];

#pragma unroll
  for (int v = 0; v < 16; ++v) {
    int rloc = (v & 3) + 8 * (v >> 2) + 4 * hi;
    int row = wr * 32 + rloc;
    float b1 = 1e30f; int i1 = 0x7fffffff;
#pragma unroll
    for (int ct = 0; ct < 4; ++ct) {
      float sc = e2v[ct] - 2.0f * acc[ct][v];
      int col = wc * 128 + ct * 32 + lr;
      if (sc < b1) { b1 = sc; i1 = col; }
    }
#pragma unroll
    for (int m = 1; m < 32; m <<= 1) {     // within 32-lane halves (hi preserved)
      float ob = __shfl_xor(b1, m);
      int   oi = __shfl_xor(i1, m);
      if (ob < b1 || (ob == b1 && oi < i1)) { b1 = ob; i1 = oi; }
    }
    float b2 = 1e30f;
#pragma unroll
    for (int ct = 0; ct < 4; ++ct) {
      float sc = e2v[ct] - 2.0f * acc[ct][v];
      int col = wc * 128 + ct * 32 + lr;
      if (col != i1 && sc < b2) b2 = sc;
    }
#pragma unroll
    for (int m = 1; m < 32; m <<= 1) {
      float ob = __shfl_xor(b2, m);
      if (ob < b2) b2 = ob;
    }
    if (lr == 0) {
      ep->b1[wc][row] = b1; ep->i1[wc][row] = i1; ep->b2[wc][row] = b2;
    }
  }
  __syncthreads();

  // merge col-halves; idx/flag; per-row loss = xx + b1
  double lrow = 0.0;
  if (tid < TM) {
    float a1 = ep->b1[0][tid], a2 = ep->b2[0][tid];
    int   ai = ep->i1[0][tid];
    float c1 = ep->b1[1][tid], c2 = ep->b2[1][tid];
    int   ci = ep->i1[1][tid];
    float b1; int i1; float b2;
    if (c1 < a1 || (c1 == a1 && ci < ai)) {
      b1 = c1; i1 = ci; b2 = (a1 < c2) ? a1 : c2;
    } else {
      b1 = a1; i1 = ai; b2 = (c1 < a2) ? c1 : a2;
    }
    ep->idx[tid] = i1;
    IDXO[row0 + tid] = (float)i1;
    FLAG[row0 + tid] = (b2 - b1 < FLAG_MARGIN) ? 1 : 0;
    lrow = (double)ep->xx[tid] + (double)b1;
  }
  if (tid < 64) {
#pragma unroll
    for (int m = 1; m < 64; m <<= 1) lrow += __shfl_xor(lrow, m);
    if (tid == 0) PART[bid] = lrow;
  }
  __syncthreads();

  // ---- output: q = cb[idx] (pure gather+write; no X re-read) ----
  const float4* CB4 = reinterpret_cast<const float4*>(CBF32);
  float4* Q4 = reinterpret_cast<float4*>(Q);
  for (int i = tid; i < TM * DD4; i += 256) {
    int r = i / DD4;
    int cc = i - r * DD4;
    Q4[(row0 + (size_t)r) * DD4 + cc] = CB4[(size_t)ep->idx[r] * DD4 + cc];
  }
}

// ---------------- phase 2: numpy-exact refine, all 3 levels, one launch -----
__global__ __launch_bounds__(256) void vq_refine(
    const float* __restrict__ X0, const float* __restrict__ X1, const float* __restrict__ X2,
    const float* __restrict__ C0, const float* __restrict__ C1, const float* __restrict__ C2,
    const float* __restrict__ E2A,
    const unsigned char* __restrict__ F0, const unsigned char* __restrict__ F1,
    const unsigned char* __restrict__ F2,
    int r0, int r1, int r2,
    float* __restrict__ Q0, float* __restrict__ Q1, float* __restrict__ Q2,
    float* __restrict__ I0, float* __restrict__ I1, float* __restrict__ I2,
    double* __restrict__ DELTA)
{
  const int lane   = threadIdx.x & 63;
  const int gwave  = (blockIdx.x * blockDim.x + threadIdx.x) >> 6;
  const int nwaves = (gridDim.x * blockDim.x) >> 6;
  const int ntot = r0 + r1 + r2;

  for (int base = gwave * 64; base < ntot; base += nwaves * 64) {
    int lvl, lb;
    const float *X, *CB; const unsigned char* FLAG; float *Q, *IDXO;
    if (base < r0)           { lvl = 0; lb = base;            X = X0; CB = C0; FLAG = F0; Q = Q0; IDXO = I0; }
    else if (base < r0 + r1) { lvl = 1; lb = base - r0;       X = X1; CB = C1; FLAG = F1; Q = Q1; IDXO = I1; }
    else                     { lvl = 2; lb = base - r0 - r1;  X = X2; CB = C2; FLAG = F2; Q = Q2; IDXO = I2; }
    const float* E2EMU = E2A + lvl * KN;

    unsigned char f = FLAG[lb + lane];
    unsigned long long mask = __ballot(f != 0);
    while (mask) {
      int bit = __ffsll((long long)mask) - 1;
      mask &= mask - 1;
      const int r = lb + bit;
      const float* xr = X + (size_t)r * DD;
      const float xx = emu_sq_pairwise384(xr);

      float best = 1e30f; int bidx = 0x7fffffff;
#pragma unroll
      for (int t = 0; t < 4; ++t) {
        int k = lane * 4 + t;
        const float* ck = CB + (size_t)k * DD;
        float E = emu_dot384_np(xr, ck);
        float s = __fadd_rn(__fsub_rn(xx, __fmul_rn(2.0f, E)), E2EMU[k]);
        if (s < best || (s == best && k < bidx)) { best = s; bidx = k; }
      }
#pragma unroll
      for (int m = 1; m < 64; m <<= 1) {
        float ob = __shfl_xor(best, m);
        int   oi = __shfl_xor(bidx, m);
        if (ob < best || (ob == best && oi < bidx)) { best = ob; bidx = oi; }
      }

      const int old = (int)IDXO[r];
      if (bidx != old) {
        const float* cn = CB + (size_t)bidx * DD;
        const float* co = CB + (size_t)old * DD;
        double dl = 0.0;
        for (int d = lane; d < DD; d += 64) {
          float xv = xr[d];
          float qn = cn[d], qo = co[d];
          Q[(size_t)r * DD + d] = qn;
          double en = (double)qn - (double)xv;
          double eo = (double)qo - (double)xv;
          dl += en * en - eo * eo;
        }
#pragma unroll
        for (int m = 1; m < 64; m <<= 1) dl += __shfl_xor(dl, m);
        if (lane == 0) {
          atomicAdd(DELTA + lvl, dl);
          IDXO[r] = (float)bidx;
        }
      }
    }
  }
}

// ---------------- loss finalize ----------------
__global__ void finalize_kernel(const double* __restrict__ p0, int n0, double w0,
                                const double* __restrict__ p1, int n1, double w1,
                                const double* __restrict__ p2, int n2, double w2,
                                const double* __restrict__ delta,
                                float* __restrict__ out) {
  __shared__ double red[4];
  int tid = threadIdx.x;
  double s0 = 0.0, s1 = 0.0, s2 = 0.0;
  for (int i = tid; i < n0; i += 256) s0 += p0[i];
  for (int i = tid; i < n1; i += 256) s1 += p1[i];
  for (int i = tid; i < n2; i += 256) s2 += p2[i];
  double v = s0 * w0 + s1 * w1 + s2 * w2;
#pragma unroll
  for (int m = 1; m < 64; m <<= 1) v += __shfl_xor(v, m);
  if ((tid & 63) == 0) red[tid >> 6] = v;
  __syncthreads();
  if (tid == 0)
    out[0] = (float)(red[0] + red[1] + red[2] + red[3]
                     + delta[0] * w0 + delta[1] * w1 + delta[2] * w2);
}

extern "C" void kernel_launch(void* const* d_in, const int* in_sizes, int n_in,
                              void* d_out, int out_size, void* d_ws, size_t ws_size,
                              hipStream_t stream) {
  const float* l0  = (const float*)d_in[0];
  const float* l1  = (const float*)d_in[1];
  const float* l2  = (const float*)d_in[2];
  const float* cb0 = (const float*)d_in[3];
  const float* cb1 = (const float*)d_in[4];
  const float* cb2 = (const float*)d_in[5];

  const size_t n_q0 = (size_t)in_sizes[0];
  const size_t n_q1 = (size_t)in_sizes[1];
  const size_t n_q2 = (size_t)in_sizes[2];
  const int r0 = (int)(n_q0 / DD);   // 65536
  const int r1 = (int)(n_q1 / DD);   // 262144
  const int r2 = (int)(n_q2 / DD);   // 262144

  float* out   = (float*)d_out;
  float* q0    = out;
  float* q1    = q0 + n_q0;
  float* q2    = q1 + n_q1;
  float* lossp = q2 + n_q2;
  float* idx0  = lossp + 1;
  float* idx1  = idx0 + r0;
  float* idx2  = idx1 + r1;

  // ws layout
  float*  e2    = (float*)d_ws;                          // 3*256 f32
  double* part  = (double*)((char*)d_ws + 4096);         // 9216 doubles
  double* delta = (double*)((char*)d_ws + 4096 + 73728);
  unsigned char* flag0 = (unsigned char*)d_ws + 4096 + 73728 + 1024;
  unsigned char* flag1 = flag0 + r0;
  unsigned char* flag2 = flag1 + r1;
  short* cbf0 = (short*)((char*)d_ws + (1 << 20));       // 3 x 384 KiB

  const int nb0 = r0 / TM, nb1 = r1 / TM, nb2 = r2 / TM;  // 1024/4096/4096
  double* p0 = part;
  double* p1 = p0 + nb0;
  double* p2 = p1 + nb1;

  prep_kernel<<<147, 256, 0, stream>>>(cb0, cb1, cb2, e2, delta, cbf0);

  vq_main<<<nb0 + nb1 + nb2, 256, 0, stream>>>(
      l0, l1, l2, cb0, cb1, cb2, cbf0, e2,
      q0, idx0, flag0, part, nb0, nb1);

  vq_refine<<<512, 256, 0, stream>>>(l0, l1, l2, cb0, cb1, cb2, e2,
                                     flag0, flag1, flag2, r0, r1, r2,
                                     q0, q1, q2, idx0, idx1, idx2, delta);

  const double w0 = 0.05 / ((double)r0 * DD);
  const double w1 = 0.25 / ((double)r1 * DD);
  const double w2 = 0.60 / ((double)r2 * DD);
  finalize_kernel<<<1, 256, 0, stream>>>(p0, nb0, w0, p1, nb1, w1, p2, nb2, w2,
                                         delta, lossp);
}

// Round 19
// 770.373 us; speedup vs baseline: 1.4189x; 1.3071x over previous
//
#include <hip/hip_runtime.h>

static constexpr int KN  = 256;   // codebook entries
static constexpr int DD  = 384;   // feature dim
static constexpr int DD4 = 96;    // DD/4
static constexpr int TM  = 64;    // rows per block (64x256 block tile)
#define FLAG_MARGIN 0.005f

typedef __attribute__((ext_vector_type(8)))  short bf16x8;   // 8 bf16 = 4 VGPR
typedef __attribute__((ext_vector_type(16))) float f32x16;   // MFMA 32x32 acc
typedef __attribute__((ext_vector_type(4)))  short short4v;

__device__ __forceinline__ unsigned short f2bf_rne(float x) {
  unsigned u = __float_as_uint(x);
  return (unsigned short)((u + 0x7fffu + ((u >> 16) & 1u)) >> 16);
}

// async global->LDS, 16B per lane (dest = wave-uniform base + lane*16)
__device__ __forceinline__ void g2lds16(const void* g, void* l) {
  __builtin_amdgcn_global_load_lds(
      (const __attribute__((address_space(1))) unsigned int*)g,
      (__attribute__((address_space(3))) unsigned int*)l, 16, 0, 0);
}

// ======== numpy-fp32 emulation helpers (VALIDATED round 4 — do not touch) ====
__device__ __forceinline__ float emu_sq_pairwise384(const float* __restrict__ p) {
  float S[4];
#pragma unroll
  for (int blk = 0; blk < 4; ++blk) {
    const float* b = p + blk * 96;
    float r[8];
#pragma unroll
    for (int l = 0; l < 8; ++l) r[l] = __fmul_rn(b[l], b[l]);
    for (int j = 8; j < 96; j += 8) {
#pragma unroll
      for (int l = 0; l < 8; ++l) r[l] = __fadd_rn(r[l], __fmul_rn(b[j + l], b[j + l]));
    }
    float t1 = __fadd_rn(__fadd_rn(r[0], r[1]), __fadd_rn(r[2], r[3]));
    float t2 = __fadd_rn(__fadd_rn(r[4], r[5]), __fadd_rn(r[6], r[7]));
    S[blk] = __fadd_rn(t1, t2);
  }
  return __fadd_rn(__fadd_rn(S[0], S[1]), __fadd_rn(S[2], S[3]));
}

__device__ __forceinline__ float emu_dot384_np(const float* __restrict__ x,
                                               const float* __restrict__ c) {
  float s[16];
#pragma unroll
  for (int t = 0; t < 16; ++t) s[t] = 0.f;
  for (int j = 0; j < 384; j += 16) {
#pragma unroll
    for (int t = 0; t < 16; ++t)
      s[t] = __fadd_rn(__fmul_rn(x[j + t], c[j + t]), s[t]);
  }
  float w0 = __fadd_rn(__fadd_rn(s[0], s[4]), __fadd_rn(s[8],  s[12]));
  float w1 = __fadd_rn(__fadd_rn(s[1], s[5]), __fadd_rn(s[9],  s[13]));
  float w2 = __fadd_rn(__fadd_rn(s[2], s[6]), __fadd_rn(s[10], s[14]));
  float w3 = __fadd_rn(__fadd_rn(s[3], s[7]), __fadd_rn(s[11], s[15]));
  return __fadd_rn(__fadd_rn(w0, w1), __fadd_rn(w2, w3));
}

// ---------------- prep: codebook norms (3 blocks) + bf16-split (144 blocks) --
__global__ __launch_bounds__(256) void prep_kernel(const float* __restrict__ c0,
                                                   const float* __restrict__ c1,
                                                   const float* __restrict__ c2,
                                                   float* __restrict__ e2,
                                                   double* __restrict__ delta,
                                                   short* __restrict__ fragbase) {
  int bid = blockIdx.x;
  if (bid < 3) {
    const float* cb = (bid == 0) ? c0 : ((bid == 1) ? c1 : c2);
    e2[bid * KN + threadIdx.x] = emu_sq_pairwise384(cb + (size_t)threadIdx.x * DD);
    if (threadIdx.x == 0) delta[bid] = 0.0;
    return;
  }
  int sb = bid - 3;                 // 0..143
  int lvl = sb / 48;
  int blk48 = sb - lvl * 48;
  const float* cb = (lvl == 0) ? c0 : ((lvl == 1) ? c1 : c2);
  short* frag = fragbase + (size_t)lvl * 196608;
  int gid = blk48 * 256 + threadIdx.x;            // 12288 = 256 entries * 48 groups
  int e = gid / 48;
  int g = gid - e * 48;
  const float4* s4 = reinterpret_cast<const float4*>(cb) + (size_t)e * 96 + g * 2;
  float4 v0 = s4[0], v1 = s4[1];
  float xs[8] = {v0.x, v0.y, v0.z, v0.w, v1.x, v1.y, v1.z, v1.w};
  short h[8], l[8];
#pragma unroll
  for (int i = 0; i < 8; ++i) {
    h[i] = (short)f2bf_rne(xs[i]);
    float hf = __uint_as_float((unsigned)(unsigned short)h[i] << 16);
    l[i] = (short)f2bf_rne(xs[i] - hf);
  }
  int c = g >> 2, rem = g & 3, ks = rem >> 1, hs = rem & 1;
  int t = e >> 5, lane = (e & 31) + (hs << 5);
  size_t blk = (((size_t)(c * 8 + t) * 2 + ks) * 2);
  short* dh = frag + blk * 512 + lane * 8;
  short* dl = dh + 512;
  *reinterpret_cast<bf16x8*>(dh) = *reinterpret_cast<const bf16x8*>(h);
  *reinterpret_cast<bf16x8*>(dl) = *reinterpret_cast<const bf16x8*>(l);
}

// ---------------- phase 1: merged 3-level MFMA GEMM + argmin + flag ---------
// r12 build restored verbatim (best known: vq_main 710us, total 771us).
__global__ __launch_bounds__(256) void vq_main(
    const float* __restrict__ X0, const float* __restrict__ X1, const float* __restrict__ X2,
    const float* __restrict__ C0, const float* __restrict__ C1, const float* __restrict__ C2,
    const short* __restrict__ FRAGBASE,
    const float* __restrict__ E2A,
    float* __restrict__ QBASE,
    float* __restrict__ IDXBASE,
    unsigned char* __restrict__ FLAGBASE,
    double* __restrict__ PART,
    int nb0, int nb1)
{
  __shared__ __align__(16) short cb_lds[16384];  // 32KB: [t(8)][ks(2)][hl(2)] 1KB blocks
  __shared__ __align__(16) short x_lds[4224];    // 8.25KB: 8 blocks x 528 shorts
  __shared__ int idx_s[TM];
  __shared__ float xx_s[TM];
  __shared__ float cand_b1[2][TM];
  __shared__ int   cand_i1[2][TM];
  __shared__ float cand_b2[2][TM];

  const int bid = blockIdx.x;
  int lvl, lb;
  if (bid < nb0)            { lvl = 0; lb = bid; }
  else if (bid < nb0 + nb1) { lvl = 1; lb = bid - nb0; }
  else                      { lvl = 2; lb = bid - nb0 - nb1; }
  const float* X  = (lvl == 0) ? X0 : ((lvl == 1) ? X1 : X2);
  const float* CBF32 = (lvl == 0) ? C0 : ((lvl == 1) ? C1 : C2);
  const short* CBFRAG = FRAGBASE + (size_t)lvl * 196608;
  const float* E2 = E2A + lvl * KN;
  const size_t rowbase = (lvl == 0) ? 0 : ((lvl == 1) ? (size_t)nb0 * TM
                                                      : (size_t)(nb0 + nb1) * TM);
  float* Q = QBASE + rowbase * DD;
  float* IDXO = IDXBASE + rowbase;
  unsigned char* FLAG = FLAGBASE + rowbase;
  const size_t row0 = (size_t)lb * TM;

  const float4* X4 = reinterpret_cast<const float4*>(X);

  f32x16 acc[4];
  {
    f32x16 z;
#pragma unroll
    for (int i = 0; i < 16; ++i) z[i] = 0.f;
#pragma unroll
    for (int ct = 0; ct < 4; ++ct) acc[ct] = z;
  }
  const int tid  = threadIdx.x;
  const int wid  = tid >> 6, lane = tid & 63;
  const int lr   = lane & 31, hi = lane >> 5;
  const int wr   = wid >> 1, wc = wid & 1;
  float xx0 = 0.f, xx1 = 0.f;   // row-norm partials (rows tid>>3 and (tid>>3)+32)

#pragma unroll 1
  for (int c = 0; c < 12; ++c) {
    // stage CB chunk: async global->LDS, 8 x 16B per thread, linear
    {
      const char* gsrc = (const char*)CBFRAG + (size_t)c * 32768 + tid * 16;
#pragma unroll
      for (int s = 0; s < 8; ++s)
        g2lds16(gsrc + s * 4096, (char*)cb_lds + tid * 16 + s * 4096);
    }
    // stage X chunk: 64 rows x 32 k fp32 -> bf16 h/l, fragment-ordered, padded
#pragma unroll
    for (int i = 0; i < 2; ++i) {
      int idx = tid + i * 256;
      int r = idx >> 3, k4 = idx & 7;
      float4 v = X4[(row0 + (size_t)r) * DD4 + c * 8 + k4];
      float pp = v.x * v.x + v.y * v.y + v.z * v.z + v.w * v.w;
      if (i == 0) xx0 += pp; else xx1 += pp;
      float xs[4] = {v.x, v.y, v.z, v.w};
      short h[4], l[4];
#pragma unroll
      for (int e = 0; e < 4; ++e) {
        h[e] = (short)f2bf_rne(xs[e]);
        float hf = __uint_as_float((unsigned)(unsigned short)h[e] << 16);
        l[e] = (short)f2bf_rne(xs[e] - hf);
      }
      int rt = r >> 5, ks = k4 >> 2, hs = (k4 >> 1) & 1;
      int off_h = ((rt * 2 + ks) * 2) * 528 + hs * 264 + (r & 31) * 8 + (k4 & 1) * 4;
      *reinterpret_cast<short4v*>(&x_lds[off_h])       = *reinterpret_cast<short4v*>(h);
      *reinterpret_cast<short4v*>(&x_lds[off_h + 528]) = *reinterpret_cast<short4v*>(l);
    }
    __syncthreads();

#pragma unroll 1
    for (int ks = 0; ks < 2; ++ks) {
      const int abase = ((wr * 2 + ks) * 2) * 528 + hi * 264 + lr * 8;
      bf16x8 ah = *reinterpret_cast<const bf16x8*>(&x_lds[abase]);
      bf16x8 al = *reinterpret_cast<const bf16x8*>(&x_lds[abase + 528]);
      const bf16x8* bb = reinterpret_cast<const bf16x8*>(cb_lds);
#pragma unroll
      for (int ct = 0; ct < 4; ++ct) {
        int t = wc * 4 + ct;
        bf16x8 bh = bb[((t * 2 + ks) * 2 + 0) * 64 + lane];
        bf16x8 bl = bb[((t * 2 + ks) * 2 + 1) * 64 + lane];
        acc[ct] = __builtin_amdgcn_mfma_f32_32x32x16_bf16(ah, bh, acc[ct], 0, 0, 0);
        acc[ct] = __builtin_amdgcn_mfma_f32_32x32x16_bf16(ah, bl, acc[ct], 0, 0, 0);
        acc[ct] = __builtin_amdgcn_mfma_f32_32x32x16_bf16(al, bh, acc[ct], 0, 0, 0);
      }
    }
    __syncthreads();
  }

  // ---- row norms: reduce 8-thread groups, park in LDS ----
#pragma unroll
  for (int m = 1; m < 8; m <<= 1) {
    xx0 += __shfl_xor(xx0, m);
    xx1 += __shfl_xor(xx1, m);
  }
  if ((lane & 7) == 0) {
    xx_s[tid >> 3]        = xx0;
    xx_s[(tid >> 3) + 32] = xx1;
  }

  // ---- argmin epilogue: D layout col=lane&31, row=(v&3)+8*(v>>2)+4*hi ----
  float e2v[4];
#pragma unroll
  for (int ct = 0; ct < 4; ++ct) e2v[ct] = E2[wc * 128 + ct * 32 + lr];

#pragma unroll
  for (int v = 0; v < 16; ++v) {
    int rloc = (v & 3) + 8 * (v >> 2) + 4 * hi;
    int row = wr * 32 + rloc;
    float b1 = 1e30f; int i1 = 0x7fffffff;
#pragma unroll
    for (int ct = 0; ct < 4; ++ct) {
      float sc = e2v[ct] - 2.0f * acc[ct][v];
      int col = wc * 128 + ct * 32 + lr;
      if (sc < b1) { b1 = sc; i1 = col; }
    }
#pragma unroll
    for (int m = 1; m < 32; m <<= 1) {     // within 32-lane halves (hi preserved)
      float ob = __shfl_xor(b1, m);
      int   oi = __shfl_xor(i1, m);
      if (ob < b1 || (ob == b1 && oi < i1)) { b1 = ob; i1 = oi; }
    }
    float b2 = 1e30f;
#pragma unroll
    for (int ct = 0; ct < 4; ++ct) {
      float sc = e2v[ct] - 2.0f * acc[ct][v];
      int col = wc * 128 + ct * 32 + lr;
      if (col != i1 && sc < b2) b2 = sc;
    }
#pragma unroll
    for (int m = 1; m < 32; m <<= 1) {
      float ob = __shfl_xor(b2, m);
      if (ob < b2) b2 = ob;
    }
    if (lr == 0) {
      cand_b1[wc][row] = b1; cand_i1[wc][row] = i1; cand_b2[wc][row] = b2;
    }
  }
  __syncthreads();

  // merge col-halves; idx/flag; per-row loss = xx + b1
  double lrow = 0.0;
  if (tid < TM) {
    float a1 = cand_b1[0][tid], a2 = cand_b2[0][tid];
    int   ai = cand_i1[0][tid];
    float c1 = cand_b1[1][tid], c2 = cand_b2[1][tid];
    int   ci = cand_i1[1][tid];
    float b1; int i1; float b2;
    if (c1 < a1 || (c1 == a1 && ci < ai)) {
      b1 = c1; i1 = ci; b2 = (a1 < c2) ? a1 : c2;
    } else {
      b1 = a1; i1 = ai; b2 = (c1 < a2) ? c1 : a2;
    }
    idx_s[tid] = i1;
    IDXO[row0 + tid] = (float)i1;
    FLAG[row0 + tid] = (b2 - b1 < FLAG_MARGIN) ? 1 : 0;
    lrow = (double)xx_s[tid] + (double)b1;
  }
  if (tid < 64) {
#pragma unroll
    for (int m = 1; m < 64; m <<= 1) lrow += __shfl_xor(lrow, m);
    if (tid == 0) PART[bid] = lrow;
  }
  __syncthreads();

  // ---- output: q = cb[idx] (pure gather+write; no X re-read) ----
  const float4* CB4 = reinterpret_cast<const float4*>(CBF32);
  float4* Q4 = reinterpret_cast<float4*>(Q);
  for (int i = tid; i < TM * DD4; i += 256) {
    int r = i / DD4;
    int cc = i - r * DD4;
    Q4[(row0 + (size_t)r) * DD4 + cc] = CB4[(size_t)idx_s[r] * DD4 + cc];
  }
}

// ---------------- phase 2: numpy-exact refine, all 3 levels, one launch -----
__global__ __launch_bounds__(256) void vq_refine(
    const float* __restrict__ X0, const float* __restrict__ X1, const float* __restrict__ X2,
    const float* __restrict__ C0, const float* __restrict__ C1, const float* __restrict__ C2,
    const float* __restrict__ E2A,
    const unsigned char* __restrict__ F0, const unsigned char* __restrict__ F1,
    const unsigned char* __restrict__ F2,
    int r0, int r1, int r2,
    float* __restrict__ Q0, float* __restrict__ Q1, float* __restrict__ Q2,
    float* __restrict__ I0, float* __restrict__ I1, float* __restrict__ I2,
    double* __restrict__ DELTA)
{
  const int lane   = threadIdx.x & 63;
  const int gwave  = (blockIdx.x * blockDim.x + threadIdx.x) >> 6;
  const int nwaves = (gridDim.x * blockDim.x) >> 6;
  const int ntot = r0 + r1 + r2;

  for (int base = gwave * 64; base < ntot; base += nwaves * 64) {
    int lvl, lb;
    const float *X, *CB; const unsigned char* FLAG; float *Q, *IDXO;
    if (base < r0)           { lvl = 0; lb = base;            X = X0; CB = C0; FLAG = F0; Q = Q0; IDXO = I0; }
    else if (base < r0 + r1) { lvl = 1; lb = base - r0;       X = X1; CB = C1; FLAG = F1; Q = Q1; IDXO = I1; }
    else                     { lvl = 2; lb = base - r0 - r1;  X = X2; CB = C2; FLAG = F2; Q = Q2; IDXO = I2; }
    const float* E2EMU = E2A + lvl * KN;

    unsigned char f = FLAG[lb + lane];
    unsigned long long mask = __ballot(f != 0);
    while (mask) {
      int bit = __ffsll((long long)mask) - 1;
      mask &= mask - 1;
      const int r = lb + bit;
      const float* xr = X + (size_t)r * DD;
      const float xx = emu_sq_pairwise384(xr);

      float best = 1e30f; int bidx = 0x7fffffff;
#pragma unroll
      for (int t = 0; t < 4; ++t) {
        int k = lane * 4 + t;
        const float* ck = CB + (size_t)k * DD;
        float E = emu_dot384_np(xr, ck);
        float s = __fadd_rn(__fsub_rn(xx, __fmul_rn(2.0f, E)), E2EMU[k]);
        if (s < best || (s == best && k < bidx)) { best = s; bidx = k; }
      }
#pragma unroll
      for (int m = 1; m < 64; m <<= 1) {
        float ob = __shfl_xor(best, m);
        int   oi = __shfl_xor(bidx, m);
        if (ob < best || (ob == best && oi < bidx)) { best = ob; bidx = oi; }
      }

      const int old = (int)IDXO[r];
      if (bidx != old) {
        const float* cn = CB + (size_t)bidx * DD;
        const float* co = CB + (size_t)old * DD;
        double dl = 0.0;
        for (int d = lane; d < DD; d += 64) {
          float xv = xr[d];
          float qn = cn[d], qo = co[d];
          Q[(size_t)r * DD + d] = qn;
          double en = (double)qn - (double)xv;
          double eo = (double)qo - (double)xv;
          dl += en * en - eo * eo;
        }
#pragma unroll
        for (int m = 1; m < 64; m <<= 1) dl += __shfl_xor(dl, m);
        if (lane == 0) {
          atomicAdd(DELTA + lvl, dl);
          IDXO[r] = (float)bidx;
        }
      }
    }
  }
}

// ---------------- loss finalize ----------------
__global__ void finalize_kernel(const double* __restrict__ p0, int n0, double w0,
                                const double* __restrict__ p1, int n1, double w1,
                                const double* __restrict__ p2, int n2, double w2,
                                const double* __restrict__ delta,
                                float* __restrict__ out) {
  __shared__ double red[4];
  int tid = threadIdx.x;
  double s0 = 0.0, s1 = 0.0, s2 = 0.0;
  for (int i = tid; i < n0; i += 256) s0 += p0[i];
  for (int i = tid; i < n1; i += 256) s1 += p1[i];
  for (int i = tid; i < n2; i += 256) s2 += p2[i];
  double v = s0 * w0 + s1 * w1 + s2 * w2;
#pragma unroll
  for (int m = 1; m < 64; m <<= 1) v += __shfl_xor(v, m);
  if ((tid & 63) == 0) red[tid >> 6] = v;
  __syncthreads();
  if (tid == 0)
    out[0] = (float)(red[0] + red[1] + red[2] + red[3]
                     + delta[0] * w0 + delta[1] * w1 + delta[2] * w2);
}

extern "C" void kernel_launch(void* const* d_in, const int* in_sizes, int n_in,
                              void* d_out, int out_size, void* d_ws, size_t ws_size,
                              hipStream_t stream) {
  const float* l0  = (const float*)d_in[0];
  const float* l1  = (const float*)d_in[1];
  const float* l2  = (const float*)d_in[2];
  const float* cb0 = (const float*)d_in[3];
  const float* cb1 = (const float*)d_in[4];
  const float* cb2 = (const float*)d_in[5];

  const size_t n_q0 = (size_t)in_sizes[0];
  const size_t n_q1 = (size_t)in_sizes[1];
  const size_t n_q2 = (size_t)in_sizes[2];
  const int r0 = (int)(n_q0 / DD);   // 65536
  const int r1 = (int)(n_q1 / DD);   // 262144
  const int r2 = (int)(n_q2 / DD);   // 262144

  float* out   = (float*)d_out;
  float* q0    = out;
  float* q1    = q0 + n_q0;
  float* q2    = q1 + n_q1;
  float* lossp = q2 + n_q2;
  float* idx0  = lossp + 1;
  float* idx1  = idx0 + r0;
  float* idx2  = idx1 + r1;

  // ws layout
  float*  e2    = (float*)d_ws;                          // 3*256 f32
  double* part  = (double*)((char*)d_ws + 4096);         // 9216 doubles
  double* delta = (double*)((char*)d_ws + 4096 + 73728);
  unsigned char* flag0 = (unsigned char*)d_ws + 4096 + 73728 + 1024;
  unsigned char* flag1 = flag0 + r0;
  unsigned char* flag2 = flag1 + r1;
  short* cbf0 = (short*)((char*)d_ws + (1 << 20));       // 3 x 384 KiB

  const int nb0 = r0 / TM, nb1 = r1 / TM, nb2 = r2 / TM;  // 1024/4096/4096
  double* p0 = part;
  double* p1 = p0 + nb0;
  double* p2 = p1 + nb1;

  prep_kernel<<<147, 256, 0, stream>>>(cb0, cb1, cb2, e2, delta, cbf0);

  vq_main<<<nb0 + nb1 + nb2, 256, 0, stream>>>(
      l0, l1, l2, cb0, cb1, cb2, cbf0, e2,
      q0, idx0, flag0, part, nb0, nb1);

  vq_refine<<<512, 256, 0, stream>>>(l0, l1, l2, cb0, cb1, cb2, e2,
                                     flag0, flag1, flag2, r0, r1, r2,
                                     q0, q1, q2, idx0, idx1, idx2, delta);

  const double w0 = 0.05 / ((double)r0 * DD);
  const double w1 = 0.25 / ((double)r1 * DD);
  const double w2 = 0.60 / ((double)r2 * DD);
  finalize_kernel<<<1, 256, 0, stream>>>(p0, nb0, w0, p1, nb1, w1, p2, nb2, w2,
                                         delta, lossp);
}

// Round 20
// 738.092 us; speedup vs baseline: 1.4809x; 1.0437x over previous
//
#include <hip/hip_runtime.h>

static constexpr int KN  = 256;   // codebook entries
static constexpr int DD  = 384;   // feature dim
static constexpr int DD4 = 96;    // DD/4
static constexpr int TM  = 64;    // rows per block (64x256 block tile)
#define FLAG_MARGIN 0.005f

typedef __attribute__((ext_vector_type(8)))  short bf16x8;   // 8 bf16 = 4 VGPR
typedef __attribute__((ext_vector_type(16))) float f32x16;   // MFMA 32x32 acc
typedef __attribute__((ext_vector_type(4)))  short short4v;
typedef __attribute__((ext_vector_type(4)))  float f32x4;

__device__ __forceinline__ unsigned short f2bf_rne(float x) {
  unsigned u = __float_as_uint(x);
  return (unsigned short)((u + 0x7fffu + ((u >> 16) & 1u)) >> 16);
}

// async global->LDS, 16B per lane (dest = wave-uniform base + lane*16)
__device__ __forceinline__ void g2lds16(const void* g, void* l) {
  __builtin_amdgcn_global_load_lds(
      (const __attribute__((address_space(1))) unsigned int*)g,
      (__attribute__((address_space(3))) unsigned int*)l, 16, 0, 0);
}

// ======== numpy-fp32 emulation helpers (VALIDATED round 4 — do not touch) ====
__device__ __forceinline__ float emu_sq_pairwise384(const float* __restrict__ p) {
  float S[4];
#pragma unroll
  for (int blk = 0; blk < 4; ++blk) {
    const float* b = p + blk * 96;
    float r[8];
#pragma unroll
    for (int l = 0; l < 8; ++l) r[l] = __fmul_rn(b[l], b[l]);
    for (int j = 8; j < 96; j += 8) {
#pragma unroll
      for (int l = 0; l < 8; ++l) r[l] = __fadd_rn(r[l], __fmul_rn(b[j + l], b[j + l]));
    }
    float t1 = __fadd_rn(__fadd_rn(r[0], r[1]), __fadd_rn(r[2], r[3]));
    float t2 = __fadd_rn(__fadd_rn(r[4], r[5]), __fadd_rn(r[6], r[7]));
    S[blk] = __fadd_rn(t1, t2);
  }
  return __fadd_rn(__fadd_rn(S[0], S[1]), __fadd_rn(S[2], S[3]));
}

__device__ __forceinline__ float emu_dot384_np(const float* __restrict__ x,
                                               const float* __restrict__ c) {
  float s[16];
#pragma unroll
  for (int t = 0; t < 16; ++t) s[t] = 0.f;
  for (int j = 0; j < 384; j += 16) {
#pragma unroll
    for (int t = 0; t < 16; ++t)
      s[t] = __fadd_rn(__fmul_rn(x[j + t], c[j + t]), s[t]);
  }
  float w0 = __fadd_rn(__fadd_rn(s[0], s[4]), __fadd_rn(s[8],  s[12]));
  float w1 = __fadd_rn(__fadd_rn(s[1], s[5]), __fadd_rn(s[9],  s[13]));
  float w2 = __fadd_rn(__fadd_rn(s[2], s[6]), __fadd_rn(s[10], s[14]));
  float w3 = __fadd_rn(__fadd_rn(s[3], s[7]), __fadd_rn(s[11], s[15]));
  return __fadd_rn(__fadd_rn(w0, w1), __fadd_rn(w2, w3));
}

// ---------------- prep: codebook norms (3 blocks) + bf16-split (144 blocks) --
__global__ __launch_bounds__(256) void prep_kernel(const float* __restrict__ c0,
                                                   const float* __restrict__ c1,
                                                   const float* __restrict__ c2,
                                                   float* __restrict__ e2,
                                                   double* __restrict__ delta,
                                                   short* __restrict__ fragbase) {
  int bid = blockIdx.x;
  if (bid < 3) {
    const float* cb = (bid == 0) ? c0 : ((bid == 1) ? c1 : c2);
    e2[bid * KN + threadIdx.x] = emu_sq_pairwise384(cb + (size_t)threadIdx.x * DD);
    if (threadIdx.x == 0) delta[bid] = 0.0;
    return;
  }
  int sb = bid - 3;                 // 0..143
  int lvl = sb / 48;
  int blk48 = sb - lvl * 48;
  const float* cb = (lvl == 0) ? c0 : ((lvl == 1) ? c1 : c2);
  short* frag = fragbase + (size_t)lvl * 196608;
  int gid = blk48 * 256 + threadIdx.x;            // 12288 = 256 entries * 48 groups
  int e = gid / 48;
  int g = gid - e * 48;
  const float4* s4 = reinterpret_cast<const float4*>(cb) + (size_t)e * 96 + g * 2;
  float4 v0 = s4[0], v1 = s4[1];
  float xs[8] = {v0.x, v0.y, v0.z, v0.w, v1.x, v1.y, v1.z, v1.w};
  short h[8], l[8];
#pragma unroll
  for (int i = 0; i < 8; ++i) {
    h[i] = (short)f2bf_rne(xs[i]);
    float hf = __uint_as_float((unsigned)(unsigned short)h[i] << 16);
    l[i] = (short)f2bf_rne(xs[i] - hf);
  }
  int c = g >> 2, rem = g & 3, ks = rem >> 1, hs = rem & 1;
  int t = e >> 5, lane = (e & 31) + (hs << 5);
  size_t blk = (((size_t)(c * 8 + t) * 2 + ks) * 2);
  short* dh = frag + blk * 512 + lane * 8;
  short* dl = dh + 512;
  *reinterpret_cast<bf16x8*>(dh) = *reinterpret_cast<const bf16x8*>(h);
  *reinterpret_cast<bf16x8*>(dl) = *reinterpret_cast<const bf16x8*>(l);
}

// ---------------- phase 1: merged 3-level MFMA GEMM + argmin + flag ---------
// r12 structure (best known) + nontemporal X loads / Q stores: X and Q are
// streamed-once (0.9 GB each per call) and were evicting the CB fragments
// that get restaged 12x per block through L2/L3.
__global__ __launch_bounds__(256) void vq_main(
    const float* __restrict__ X0, const float* __restrict__ X1, const float* __restrict__ X2,
    const float* __restrict__ C0, const float* __restrict__ C1, const float* __restrict__ C2,
    const short* __restrict__ FRAGBASE,
    const float* __restrict__ E2A,
    float* __restrict__ QBASE,
    float* __restrict__ IDXBASE,
    unsigned char* __restrict__ FLAGBASE,
    double* __restrict__ PART,
    int nb0, int nb1)
{
  __shared__ __align__(16) short cb_lds[16384];  // 32KB: [t(8)][ks(2)][hl(2)] 1KB blocks
  __shared__ __align__(16) short x_lds[4224];    // 8.25KB: 8 blocks x 528 shorts
  __shared__ int idx_s[TM];
  __shared__ float xx_s[TM];
  __shared__ float cand_b1[2][TM];
  __shared__ int   cand_i1[2][TM];
  __shared__ float cand_b2[2][TM];

  const int bid = blockIdx.x;
  int lvl, lb;
  if (bid < nb0)            { lvl = 0; lb = bid; }
  else if (bid < nb0 + nb1) { lvl = 1; lb = bid - nb0; }
  else                      { lvl = 2; lb = bid - nb0 - nb1; }
  const float* X  = (lvl == 0) ? X0 : ((lvl == 1) ? X1 : X2);
  const float* CBF32 = (lvl == 0) ? C0 : ((lvl == 1) ? C1 : C2);
  const short* CBFRAG = FRAGBASE + (size_t)lvl * 196608;
  const float* E2 = E2A + lvl * KN;
  const size_t rowbase = (lvl == 0) ? 0 : ((lvl == 1) ? (size_t)nb0 * TM
                                                      : (size_t)(nb0 + nb1) * TM);
  float* Q = QBASE + rowbase * DD;
  float* IDXO = IDXBASE + rowbase;
  unsigned char* FLAG = FLAGBASE + rowbase;
  const size_t row0 = (size_t)lb * TM;

  const f32x4* X4 = reinterpret_cast<const f32x4*>(X);

  f32x16 acc[4];
  {
    f32x16 z;
#pragma unroll
    for (int i = 0; i < 16; ++i) z[i] = 0.f;
#pragma unroll
    for (int ct = 0; ct < 4; ++ct) acc[ct] = z;
  }
  const int tid  = threadIdx.x;
  const int wid  = tid >> 6, lane = tid & 63;
  const int lr   = lane & 31, hi = lane >> 5;
  const int wr   = wid >> 1, wc = wid & 1;
  float xx0 = 0.f, xx1 = 0.f;   // row-norm partials (rows tid>>3 and (tid>>3)+32)

#pragma unroll 1
  for (int c = 0; c < 12; ++c) {
    // stage CB chunk: async global->LDS, 8 x 16B per thread, linear
    {
      const char* gsrc = (const char*)CBFRAG + (size_t)c * 32768 + tid * 16;
#pragma unroll
      for (int s = 0; s < 8; ++s)
        g2lds16(gsrc + s * 4096, (char*)cb_lds + tid * 16 + s * 4096);
    }
    // stage X chunk: 64 rows x 32 k fp32 -> bf16 h/l (NONTEMPORAL loads)
#pragma unroll
    for (int i = 0; i < 2; ++i) {
      int idx = tid + i * 256;
      int r = idx >> 3, k4 = idx & 7;
      f32x4 v = __builtin_nontemporal_load(
          X4 + (row0 + (size_t)r) * DD4 + c * 8 + k4);
      float pp = v[0] * v[0] + v[1] * v[1] + v[2] * v[2] + v[3] * v[3];
      if (i == 0) xx0 += pp; else xx1 += pp;
      float xs[4] = {v[0], v[1], v[2], v[3]};
      short h[4], l[4];
#pragma unroll
      for (int e = 0; e < 4; ++e) {
        h[e] = (short)f2bf_rne(xs[e]);
        float hf = __uint_as_float((unsigned)(unsigned short)h[e] << 16);
        l[e] = (short)f2bf_rne(xs[e] - hf);
      }
      int rt = r >> 5, ks = k4 >> 2, hs = (k4 >> 1) & 1;
      int off_h = ((rt * 2 + ks) * 2) * 528 + hs * 264 + (r & 31) * 8 + (k4 & 1) * 4;
      *reinterpret_cast<short4v*>(&x_lds[off_h])       = *reinterpret_cast<short4v*>(h);
      *reinterpret_cast<short4v*>(&x_lds[off_h + 528]) = *reinterpret_cast<short4v*>(l);
    }
    __syncthreads();

#pragma unroll 1
    for (int ks = 0; ks < 2; ++ks) {
      const int abase = ((wr * 2 + ks) * 2) * 528 + hi * 264 + lr * 8;
      bf16x8 ah = *reinterpret_cast<const bf16x8*>(&x_lds[abase]);
      bf16x8 al = *reinterpret_cast<const bf16x8*>(&x_lds[abase + 528]);
      const bf16x8* bb = reinterpret_cast<const bf16x8*>(cb_lds);
#pragma unroll
      for (int ct = 0; ct < 4; ++ct) {
        int t = wc * 4 + ct;
        bf16x8 bh = bb[((t * 2 + ks) * 2 + 0) * 64 + lane];
        bf16x8 bl = bb[((t * 2 + ks) * 2 + 1) * 64 + lane];
        acc[ct] = __builtin_amdgcn_mfma_f32_32x32x16_bf16(ah, bh, acc[ct], 0, 0, 0);
        acc[ct] = __builtin_amdgcn_mfma_f32_32x32x16_bf16(ah, bl, acc[ct], 0, 0, 0);
        acc[ct] = __builtin_amdgcn_mfma_f32_32x32x16_bf16(al, bh, acc[ct], 0, 0, 0);
      }
    }
    __syncthreads();
  }

  // ---- row norms: reduce 8-thread groups, park in LDS ----
#pragma unroll
  for (int m = 1; m < 8; m <<= 1) {
    xx0 += __shfl_xor(xx0, m);
    xx1 += __shfl_xor(xx1, m);
  }
  if ((lane & 7) == 0) {
    xx_s[tid >> 3]        = xx0;
    xx_s[(tid >> 3) + 32] = xx1;
  }

  // ---- argmin epilogue: D layout col=lane&31, row=(v&3)+8*(v>>2)+4*hi ----
  float e2v[4];
#pragma unroll
  for (int ct = 0; ct < 4; ++ct) e2v[ct] = E2[wc * 128 + ct * 32 + lr];

#pragma unroll
  for (int v = 0; v < 16; ++v) {
    int rloc = (v & 3) + 8 * (v >> 2) + 4 * hi;
    int row = wr * 32 + rloc;
    float b1 = 1e30f; int i1 = 0x7fffffff;
#pragma unroll
    for (int ct = 0; ct < 4; ++ct) {
      float sc = e2v[ct] - 2.0f * acc[ct][v];
      int col = wc * 128 + ct * 32 + lr;
      if (sc < b1) { b1 = sc; i1 = col; }
    }
#pragma unroll
    for (int m = 1; m < 32; m <<= 1) {     // within 32-lane halves (hi preserved)
      float ob = __shfl_xor(b1, m);
      int   oi = __shfl_xor(i1, m);
      if (ob < b1 || (ob == b1 && oi < i1)) { b1 = ob; i1 = oi; }
    }
    float b2 = 1e30f;
#pragma unroll
    for (int ct = 0; ct < 4; ++ct) {
      float sc = e2v[ct] - 2.0f * acc[ct][v];
      int col = wc * 128 + ct * 32 + lr;
      if (col != i1 && sc < b2) b2 = sc;
    }
#pragma unroll
    for (int m = 1; m < 32; m <<= 1) {
      float ob = __shfl_xor(b2, m);
      if (ob < b2) b2 = ob;
    }
    if (lr == 0) {
      cand_b1[wc][row] = b1; cand_i1[wc][row] = i1; cand_b2[wc][row] = b2;
    }
  }
  __syncthreads();

  // merge col-halves; idx/flag; per-row loss = xx + b1
  double lrow = 0.0;
  if (tid < TM) {
    float a1 = cand_b1[0][tid], a2 = cand_b2[0][tid];
    int   ai = cand_i1[0][tid];
    float c1 = cand_b1[1][tid], c2 = cand_b2[1][tid];
    int   ci = cand_i1[1][tid];
    float b1; int i1; float b2;
    if (c1 < a1 || (c1 == a1 && ci < ai)) {
      b1 = c1; i1 = ci; b2 = (a1 < c2) ? a1 : c2;
    } else {
      b1 = a1; i1 = ai; b2 = (c1 < a2) ? c1 : a2;
    }
    idx_s[tid] = i1;
    IDXO[row0 + tid] = (float)i1;
    FLAG[row0 + tid] = (b2 - b1 < FLAG_MARGIN) ? 1 : 0;
    lrow = (double)xx_s[tid] + (double)b1;
  }
  if (tid < 64) {
#pragma unroll
    for (int m = 1; m < 64; m <<= 1) lrow += __shfl_xor(lrow, m);
    if (tid == 0) PART[bid] = lrow;
  }
  __syncthreads();

  // ---- output: q = cb[idx] — CB read cached, Q write NONTEMPORAL ----
  const f32x4* CB4 = reinterpret_cast<const f32x4*>(CBF32);
  f32x4* Q4 = reinterpret_cast<f32x4*>(Q);
  for (int i = tid; i < TM * DD4; i += 256) {
    int r = i / DD4;
    int cc = i - r * DD4;
    f32x4 qv = CB4[(size_t)idx_s[r] * DD4 + cc];
    __builtin_nontemporal_store(qv, Q4 + (row0 + (size_t)r) * DD4 + cc);
  }
}

// ---------------- phase 2: numpy-exact refine, all 3 levels, one launch -----
__global__ __launch_bounds__(256) void vq_refine(
    const float* __restrict__ X0, const float* __restrict__ X1, const float* __restrict__ X2,
    const float* __restrict__ C0, const float* __restrict__ C1, const float* __restrict__ C2,
    const float* __restrict__ E2A,
    const unsigned char* __restrict__ F0, const unsigned char* __restrict__ F1,
    const unsigned char* __restrict__ F2,
    int r0, int r1, int r2,
    float* __restrict__ Q0, float* __restrict__ Q1, float* __restrict__ Q2,
    float* __restrict__ I0, float* __restrict__ I1, float* __restrict__ I2,
    double* __restrict__ DELTA)
{
  const int lane   = threadIdx.x & 63;
  const int gwave  = (blockIdx.x * blockDim.x + threadIdx.x) >> 6;
  const int nwaves = (gridDim.x * blockDim.x) >> 6;
  const int ntot = r0 + r1 + r2;

  for (int base = gwave * 64; base < ntot; base += nwaves * 64) {
    int lvl, lb;
    const float *X, *CB; const unsigned char* FLAG; float *Q, *IDXO;
    if (base < r0)           { lvl = 0; lb = base;            X = X0; CB = C0; FLAG = F0; Q = Q0; IDXO = I0; }
    else if (base < r0 + r1) { lvl = 1; lb = base - r0;       X = X1; CB = C1; FLAG = F1; Q = Q1; IDXO = I1; }
    else                     { lvl = 2; lb = base - r0 - r1;  X = X2; CB = C2; FLAG = F2; Q = Q2; IDXO = I2; }
    const float* E2EMU = E2A + lvl * KN;

    unsigned char f = FLAG[lb + lane];
    unsigned long long mask = __ballot(f != 0);
    while (mask) {
      int bit = __ffsll((long long)mask) - 1;
      mask &= mask - 1;
      const int r = lb + bit;
      const float* xr = X + (size_t)r * DD;
      const float xx = emu_sq_pairwise384(xr);

      float best = 1e30f; int bidx = 0x7fffffff;
#pragma unroll
      for (int t = 0; t < 4; ++t) {
        int k = lane * 4 + t;
        const float* ck = CB + (size_t)k * DD;
        float E = emu_dot384_np(xr, ck);
        float s = __fadd_rn(__fsub_rn(xx, __fmul_rn(2.0f, E)), E2EMU[k]);
        if (s < best || (s == best && k < bidx)) { best = s; bidx = k; }
      }
#pragma unroll
      for (int m = 1; m < 64; m <<= 1) {
        float ob = __shfl_xor(best, m);
        int   oi = __shfl_xor(bidx, m);
        if (ob < best || (ob == best && oi < bidx)) { best = ob; bidx = oi; }
      }

      const int old = (int)IDXO[r];
      if (bidx != old) {
        const float* cn = CB + (size_t)bidx * DD;
        const float* co = CB + (size_t)old * DD;
        double dl = 0.0;
        for (int d = lane; d < DD; d += 64) {
          float xv = xr[d];
          float qn = cn[d], qo = co[d];
          Q[(size_t)r * DD + d] = qn;
          double en = (double)qn - (double)xv;
          double eo = (double)qo - (double)xv;
          dl += en * en - eo * eo;
        }
#pragma unroll
        for (int m = 1; m < 64; m <<= 1) dl += __shfl_xor(dl, m);
        if (lane == 0) {
          atomicAdd(DELTA + lvl, dl);
          IDXO[r] = (float)bidx;
        }
      }
    }
  }
}

// ---------------- loss finalize ----------------
__global__ void finalize_kernel(const double* __restrict__ p0, int n0, double w0,
                                const double* __restrict__ p1, int n1, double w1,
                                const double* __restrict__ p2, int n2, double w2,
                                const double* __restrict__ delta,
                                float* __restrict__ out) {
  __shared__ double red[4];
  int tid = threadIdx.x;
  double s0 = 0.0, s1 = 0.0, s2 = 0.0;
  for (int i = tid; i < n0; i += 256) s0 += p0[i];
  for (int i = tid; i < n1; i += 256) s1 += p1[i];
  for (int i = tid; i < n2; i += 256) s2 += p2[i];
  double v = s0 * w0 + s1 * w1 + s2 * w2;
#pragma unroll
  for (int m = 1; m < 64; m <<= 1) v += __shfl_xor(v, m);
  if ((tid & 63) == 0) red[tid >> 6] = v;
  __syncthreads();
  if (tid == 0)
    out[0] = (float)(red[0] + red[1] + red[2] + red[3]
                     + delta[0] * w0 + delta[1] * w1 + delta[2] * w2);
}

extern "C" void kernel_launch(void* const* d_in, const int* in_sizes, int n_in,
                              void* d_out, int out_size, void* d_ws, size_t ws_size,
                              hipStream_t stream) {
  const float* l0  = (const float*)d_in[0];
  const float* l1  = (const float*)d_in[1];
  const float* l2  = (const float*)d_in[2];
  const float* cb0 = (const float*)d_in[3];
  const float* cb1 = (const float*)d_in[4];
  const float* cb2 = (const float*)d_in[5];

  const size_t n_q0 = (size_t)in_sizes[0];
  const size_t n_q1 = (size_t)in_sizes[1];
  const size_t n_q2 = (size_t)in_sizes[2];
  const int r0 = (int)(n_q0 / DD);   // 65536
  const int r1 = (int)(n_q1 / DD);   // 262144
  const int r2 = (int)(n_q2 / DD);   // 262144

  float* out   = (float*)d_out;
  float* q0    = out;
  float* q1    = q0 + n_q0;
  float* q2    = q1 + n_q1;
  float* lossp = q2 + n_q2;
  float* idx0  = lossp + 1;
  float* idx1  = idx0 + r0;
  float* idx2  = idx1 + r1;

  // ws layout
  float*  e2    = (float*)d_ws;                          // 3*256 f32
  double* part  = (double*)((char*)d_ws + 4096);         // 9216 doubles
  double* delta = (double*)((char*)d_ws + 4096 + 73728);
  unsigned char* flag0 = (unsigned char*)d_ws + 4096 + 73728 + 1024;
  unsigned char* flag1 = flag0 + r0;
  unsigned char* flag2 = flag1 + r1;
  short* cbf0 = (short*)((char*)d_ws + (1 << 20));       // 3 x 384 KiB

  const int nb0 = r0 / TM, nb1 = r1 / TM, nb2 = r2 / TM;  // 1024/4096/4096
  double* p0 = part;
  double* p1 = p0 + nb0;
  double* p2 = p1 + nb1;

  prep_kernel<<<147, 256, 0, stream>>>(cb0, cb1, cb2, e2, delta, cbf0);

  vq_main<<<nb0 + nb1 + nb2, 256, 0, stream>>>(
      l0, l1, l2, cb0, cb1, cb2, cbf0, e2,
      q0, idx0, flag0, part, nb0, nb1);

  vq_refine<<<512, 256, 0, stream>>>(l0, l1, l2, cb0, cb1, cb2, e2,
                                     flag0, flag1, flag2, r0, r1, r2,
                                     q0, q1, q2, idx0, idx1, idx2, delta);

  const double w0 = 0.05 / ((double)r0 * DD);
  const double w1 = 0.25 / ((double)r1 * DD);
  const double w2 = 0.60 / ((double)r2 * DD);
  finalize_kernel<<<1, 256, 0, stream>>>(p0, nb0, w0, p1, nb1, w1, p2, nb2, w2,
                                         delta, lossp);
}

// Round 21
// 737.290 us; speedup vs baseline: 1.4825x; 1.0011x over previous
//
#include <hip/hip_runtime.h>
#include <hip/hip_bf16.h>
#include <string.h>

static constexpr int KN  = 256;   // codebook entries
static constexpr int DD  = 384;   // feature dim
static constexpr int DD4 = 96;    // DD/4
static constexpr int TM  = 64;    // rows per block (64x256 block tile)
#define FLAG_MARGIN 0.005f

typedef __attribute__((ext_vector_type(8)))  short bf16x8;   // 8 bf16 = 4 VGPR
typedef __attribute__((ext_vector_type(16))) float f32x16;   // MFMA 32x32 acc
typedef __attribute__((ext_vector_type(4)))  short short4v;
typedef __attribute__((ext_vector_type(4)))  float f32x4;
typedef __attribute__((ext_vector_type(2)))  unsigned int uint2v;

__device__ __forceinline__ unsigned short f2bf_rne(float x) {
  unsigned u = __float_as_uint(x);
  return (unsigned short)((u + 0x7fffu + ((u >> 16) & 1u)) >> 16);
}

// async global->LDS, 16B per lane (dest = wave-uniform base + lane*16)
__device__ __forceinline__ void g2lds16(const void* g, void* l) {
  __builtin_amdgcn_global_load_lds(
      (const __attribute__((address_space(1))) unsigned int*)g,
      (__attribute__((address_space(3))) unsigned int*)l, 16, 0, 0);
}

// packed pair f32->bf16 RNE (compiler emits v_cvt_pk_bf16_f32); bit-identical
// to f2bf_rne on normal values.
__device__ __forceinline__ unsigned pkbf(float a, float b) {
  __hip_bfloat162 h = __float22bfloat162_rn(float2{a, b});
  unsigned r;
  memcpy(&r, &h, 4);
  return r;
}

// ======== numpy-fp32 emulation helpers (VALIDATED round 4 — do not touch) ====
__device__ __forceinline__ float emu_sq_pairwise384(const float* __restrict__ p) {
  float S[4];
#pragma unroll
  for (int blk = 0; blk < 4; ++blk) {
    const float* b = p + blk * 96;
    float r[8];
#pragma unroll
    for (int l = 0; l < 8; ++l) r[l] = __fmul_rn(b[l], b[l]);
    for (int j = 8; j < 96; j += 8) {
#pragma unroll
      for (int l = 0; l < 8; ++l) r[l] = __fadd_rn(r[l], __fmul_rn(b[j + l], b[j + l]));
    }
    float t1 = __fadd_rn(__fadd_rn(r[0], r[1]), __fadd_rn(r[2], r[3]));
    float t2 = __fadd_rn(__fadd_rn(r[4], r[5]), __fadd_rn(r[6], r[7]));
    S[blk] = __fadd_rn(t1, t2);
  }
  return __fadd_rn(__fadd_rn(S[0], S[1]), __fadd_rn(S[2], S[3]));
}

__device__ __forceinline__ float emu_dot384_np(const float* __restrict__ x,
                                               const float* __restrict__ c) {
  float s[16];
#pragma unroll
  for (int t = 0; t < 16; ++t) s[t] = 0.f;
  for (int j = 0; j < 384; j += 16) {
#pragma unroll
    for (int t = 0; t < 16; ++t)
      s[t] = __fadd_rn(__fmul_rn(x[j + t], c[j + t]), s[t]);
  }
  float w0 = __fadd_rn(__fadd_rn(s[0], s[4]), __fadd_rn(s[8],  s[12]));
  float w1 = __fadd_rn(__fadd_rn(s[1], s[5]), __fadd_rn(s[9],  s[13]));
  float w2 = __fadd_rn(__fadd_rn(s[2], s[6]), __fadd_rn(s[10], s[14]));
  float w3 = __fadd_rn(__fadd_rn(s[3], s[7]), __fadd_rn(s[11], s[15]));
  return __fadd_rn(__fadd_rn(w0, w1), __fadd_rn(w2, w3));
}

// ---------------- prep: codebook norms (3 blocks) + bf16-split (144 blocks) --
__global__ __launch_bounds__(256) void prep_kernel(const float* __restrict__ c0,
                                                   const float* __restrict__ c1,
                                                   const float* __restrict__ c2,
                                                   float* __restrict__ e2,
                                                   double* __restrict__ delta,
                                                   short* __restrict__ fragbase) {
  int bid = blockIdx.x;
  if (bid < 3) {
    const float* cb = (bid == 0) ? c0 : ((bid == 1) ? c1 : c2);
    e2[bid * KN + threadIdx.x] = emu_sq_pairwise384(cb + (size_t)threadIdx.x * DD);
    if (threadIdx.x == 0) delta[bid] = 0.0;
    return;
  }
  int sb = bid - 3;                 // 0..143
  int lvl = sb / 48;
  int blk48 = sb - lvl * 48;
  const float* cb = (lvl == 0) ? c0 : ((lvl == 1) ? c1 : c2);
  short* frag = fragbase + (size_t)lvl * 196608;
  int gid = blk48 * 256 + threadIdx.x;            // 12288 = 256 entries * 48 groups
  int e = gid / 48;
  int g = gid - e * 48;
  const float4* s4 = reinterpret_cast<const float4*>(cb) + (size_t)e * 96 + g * 2;
  float4 v0 = s4[0], v1 = s4[1];
  float xs[8] = {v0.x, v0.y, v0.z, v0.w, v1.x, v1.y, v1.z, v1.w};
  short h[8], l[8];
#pragma unroll
  for (int i = 0; i < 8; ++i) {
    h[i] = (short)f2bf_rne(xs[i]);
    float hf = __uint_as_float((unsigned)(unsigned short)h[i] << 16);
    l[i] = (short)f2bf_rne(xs[i] - hf);
  }
  int c = g >> 2, rem = g & 3, ks = rem >> 1, hs = rem & 1;
  int t = e >> 5, lane = (e & 31) + (hs << 5);
  size_t blk = (((size_t)(c * 8 + t) * 2 + ks) * 2);
  short* dh = frag + blk * 512 + lane * 8;
  short* dl = dh + 512;
  *reinterpret_cast<bf16x8*>(dh) = *reinterpret_cast<const bf16x8*>(h);
  *reinterpret_cast<bf16x8*>(dl) = *reinterpret_cast<const bf16x8*>(l);
}

// ---------------- phase 1: merged 3-level MFMA GEMM + argmin + flag ---------
// r20 build (r12 structure + nontemporal X/Q) + packed-pair bf16 split via
// v_cvt_pk_bf16_f32 (portable intrinsic): ~4x fewer VALU ops per converted
// element; scores bit-identical (both paths are RNE).
__global__ __launch_bounds__(256) void vq_main(
    const float* __restrict__ X0, const float* __restrict__ X1, const float* __restrict__ X2,
    const float* __restrict__ C0, const float* __restrict__ C1, const float* __restrict__ C2,
    const short* __restrict__ FRAGBASE,
    const float* __restrict__ E2A,
    float* __restrict__ QBASE,
    float* __restrict__ IDXBASE,
    unsigned char* __restrict__ FLAGBASE,
    double* __restrict__ PART,
    int nb0, int nb1)
{
  __shared__ __align__(16) short cb_lds[16384];  // 32KB: [t(8)][ks(2)][hl(2)] 1KB blocks
  __shared__ __align__(16) short x_lds[4224];    // 8.25KB: 8 blocks x 528 shorts
  __shared__ int idx_s[TM];
  __shared__ float xx_s[TM];
  __shared__ float cand_b1[2][TM];
  __shared__ int   cand_i1[2][TM];
  __shared__ float cand_b2[2][TM];

  const int bid = blockIdx.x;
  int lvl, lb;
  if (bid < nb0)            { lvl = 0; lb = bid; }
  else if (bid < nb0 + nb1) { lvl = 1; lb = bid - nb0; }
  else                      { lvl = 2; lb = bid - nb0 - nb1; }
  const float* X  = (lvl == 0) ? X0 : ((lvl == 1) ? X1 : X2);
  const float* CBF32 = (lvl == 0) ? C0 : ((lvl == 1) ? C1 : C2);
  const short* CBFRAG = FRAGBASE + (size_t)lvl * 196608;
  const float* E2 = E2A + lvl * KN;
  const size_t rowbase = (lvl == 0) ? 0 : ((lvl == 1) ? (size_t)nb0 * TM
                                                      : (size_t)(nb0 + nb1) * TM);
  float* Q = QBASE + rowbase * DD;
  float* IDXO = IDXBASE + rowbase;
  unsigned char* FLAG = FLAGBASE + rowbase;
  const size_t row0 = (size_t)lb * TM;

  const f32x4* X4 = reinterpret_cast<const f32x4*>(X);

  f32x16 acc[4];
  {
    f32x16 z;
#pragma unroll
    for (int i = 0; i < 16; ++i) z[i] = 0.f;
#pragma unroll
    for (int ct = 0; ct < 4; ++ct) acc[ct] = z;
  }
  const int tid  = threadIdx.x;
  const int wid  = tid >> 6, lane = tid & 63;
  const int lr   = lane & 31, hi = lane >> 5;
  const int wr   = wid >> 1, wc = wid & 1;
  float xx0 = 0.f, xx1 = 0.f;   // row-norm partials (rows tid>>3 and (tid>>3)+32)

#pragma unroll 1
  for (int c = 0; c < 12; ++c) {
    // stage CB chunk: async global->LDS, 8 x 16B per thread, linear
    {
      const char* gsrc = (const char*)CBFRAG + (size_t)c * 32768 + tid * 16;
#pragma unroll
      for (int s = 0; s < 8; ++s)
        g2lds16(gsrc + s * 4096, (char*)cb_lds + tid * 16 + s * 4096);
    }
    // stage X chunk: nontemporal load, packed-pair bf16 h/l split
#pragma unroll
    for (int i = 0; i < 2; ++i) {
      int idx = tid + i * 256;
      int r = idx >> 3, k4 = idx & 7;
      f32x4 v = __builtin_nontemporal_load(
          X4 + (row0 + (size_t)r) * DD4 + c * 8 + k4);
      float pp = v[0] * v[0] + v[1] * v[1] + v[2] * v[2] + v[3] * v[3];
      if (i == 0) xx0 += pp; else xx1 += pp;

      unsigned hpA = pkbf(v[0], v[1]);
      unsigned hpB = pkbf(v[2], v[3]);
      float l0 = v[0] - __uint_as_float(hpA << 16);
      float l1 = v[1] - __uint_as_float(hpA & 0xffff0000u);
      float l2v = v[2] - __uint_as_float(hpB << 16);
      float l3 = v[3] - __uint_as_float(hpB & 0xffff0000u);
      unsigned lpA = pkbf(l0, l1);
      unsigned lpB = pkbf(l2v, l3);

      int rt = r >> 5, ks = k4 >> 2, hs = (k4 >> 1) & 1;
      int off_h = ((rt * 2 + ks) * 2) * 528 + hs * 264 + (r & 31) * 8 + (k4 & 1) * 4;
      uint2v hw; hw[0] = hpA; hw[1] = hpB;
      uint2v lw; lw[0] = lpA; lw[1] = lpB;
      *reinterpret_cast<uint2v*>(&x_lds[off_h])       = hw;
      *reinterpret_cast<uint2v*>(&x_lds[off_h + 528]) = lw;
    }
    __syncthreads();

#pragma unroll 1
    for (int ks = 0; ks < 2; ++ks) {
      const int abase = ((wr * 2 + ks) * 2) * 528 + hi * 264 + lr * 8;
      bf16x8 ah = *reinterpret_cast<const bf16x8*>(&x_lds[abase]);
      bf16x8 al = *reinterpret_cast<const bf16x8*>(&x_lds[abase + 528]);
      const bf16x8* bb = reinterpret_cast<const bf16x8*>(cb_lds);
#pragma unroll
      for (int ct = 0; ct < 4; ++ct) {
        int t = wc * 4 + ct;
        bf16x8 bh = bb[((t * 2 + ks) * 2 + 0) * 64 + lane];
        bf16x8 bl = bb[((t * 2 + ks) * 2 + 1) * 64 + lane];
        acc[ct] = __builtin_amdgcn_mfma_f32_32x32x16_bf16(ah, bh, acc[ct], 0, 0, 0);
        acc[ct] = __builtin_amdgcn_mfma_f32_32x32x16_bf16(ah, bl, acc[ct], 0, 0, 0);
        acc[ct] = __builtin_amdgcn_mfma_f32_32x32x16_bf16(al, bh, acc[ct], 0, 0, 0);
      }
    }
    __syncthreads();
  }

  // ---- row norms: reduce 8-thread groups, park in LDS ----
#pragma unroll
  for (int m = 1; m < 8; m <<= 1) {
    xx0 += __shfl_xor(xx0, m);
    xx1 += __shfl_xor(xx1, m);
  }
  if ((lane & 7) == 0) {
    xx_s[tid >> 3]        = xx0;
    xx_s[(tid >> 3) + 32] = xx1;
  }

  // ---- argmin epilogue: D layout col=lane&31, row=(v&3)+8*(v>>2)+4*hi ----
  float e2v[4];
#pragma unroll
  for (int ct = 0; ct < 4; ++ct) e2v[ct] = E2[wc * 128 + ct * 32 + lr];

#pragma unroll
  for (int v = 0; v < 16; ++v) {
    int rloc = (v & 3) + 8 * (v >> 2) + 4 * hi;
    int row = wr * 32 + rloc;
    float b1 = 1e30f; int i1 = 0x7fffffff;
#pragma unroll
    for (int ct = 0; ct < 4; ++ct) {
      float sc = e2v[ct] - 2.0f * acc[ct][v];
      int col = wc * 128 + ct * 32 + lr;
      if (sc < b1) { b1 = sc; i1 = col; }
    }
#pragma unroll
    for (int m = 1; m < 32; m <<= 1) {     // within 32-lane halves (hi preserved)
      float ob = __shfl_xor(b1, m);
      int   oi = __shfl_xor(i1, m);
      if (ob < b1 || (ob == b1 && oi < i1)) { b1 = ob; i1 = oi; }
    }
    float b2 = 1e30f;
#pragma unroll
    for (int ct = 0; ct < 4; ++ct) {
      float sc = e2v[ct] - 2.0f * acc[ct][v];
      int col = wc * 128 + ct * 32 + lr;
      if (col != i1 && sc < b2) b2 = sc;
    }
#pragma unroll
    for (int m = 1; m < 32; m <<= 1) {
      float ob = __shfl_xor(b2, m);
      if (ob < b2) b2 = ob;
    }
    if (lr == 0) {
      cand_b1[wc][row] = b1; cand_i1[wc][row] = i1; cand_b2[wc][row] = b2;
    }
  }
  __syncthreads();

  // merge col-halves; idx/flag; per-row loss = xx + b1
  double lrow = 0.0;
  if (tid < TM) {
    float a1 = cand_b1[0][tid], a2 = cand_b2[0][tid];
    int   ai = cand_i1[0][tid];
    float c1 = cand_b1[1][tid], c2 = cand_b2[1][tid];
    int   ci = cand_i1[1][tid];
    float b1; int i1; float b2;
    if (c1 < a1 || (c1 == a1 && ci < ai)) {
      b1 = c1; i1 = ci; b2 = (a1 < c2) ? a1 : c2;
    } else {
      b1 = a1; i1 = ai; b2 = (c1 < a2) ? c1 : a2;
    }
    idx_s[tid] = i1;
    IDXO[row0 + tid] = (float)i1;
    FLAG[row0 + tid] = (b2 - b1 < FLAG_MARGIN) ? 1 : 0;
    lrow = (double)xx_s[tid] + (double)b1;
  }
  if (tid < 64) {
#pragma unroll
    for (int m = 1; m < 64; m <<= 1) lrow += __shfl_xor(lrow, m);
    if (tid == 0) PART[bid] = lrow;
  }
  __syncthreads();

  // ---- output: q = cb[idx] — CB read cached, Q write NONTEMPORAL ----
  const f32x4* CB4 = reinterpret_cast<const f32x4*>(CBF32);
  f32x4* Q4 = reinterpret_cast<f32x4*>(Q);
  for (int i = tid; i < TM * DD4; i += 256) {
    int r = i / DD4;
    int cc = i - r * DD4;
    f32x4 qv = CB4[(size_t)idx_s[r] * DD4 + cc];
    __builtin_nontemporal_store(qv, Q4 + (row0 + (size_t)r) * DD4 + cc);
  }
}

// ---------------- phase 2: numpy-exact refine, all 3 levels, one launch -----
__global__ __launch_bounds__(256) void vq_refine(
    const float* __restrict__ X0, const float* __restrict__ X1, const float* __restrict__ X2,
    const float* __restrict__ C0, const float* __restrict__ C1, const float* __restrict__ C2,
    const float* __restrict__ E2A,
    const unsigned char* __restrict__ F0, const unsigned char* __restrict__ F1,
    const unsigned char* __restrict__ F2,
    int r0, int r1, int r2,
    float* __restrict__ Q0, float* __restrict__ Q1, float* __restrict__ Q2,
    float* __restrict__ I0, float* __restrict__ I1, float* __restrict__ I2,
    double* __restrict__ DELTA)
{
  const int lane   = threadIdx.x & 63;
  const int gwave  = (blockIdx.x * blockDim.x + threadIdx.x) >> 6;
  const int nwaves = (gridDim.x * blockDim.x) >> 6;
  const int ntot = r0 + r1 + r2;

  for (int base = gwave * 64; base < ntot; base += nwaves * 64) {
    int lvl, lb;
    const float *X, *CB; const unsigned char* FLAG; float *Q, *IDXO;
    if (base < r0)           { lvl = 0; lb = base;            X = X0; CB = C0; FLAG = F0; Q = Q0; IDXO = I0; }
    else if (base < r0 + r1) { lvl = 1; lb = base - r0;       X = X1; CB = C1; FLAG = F1; Q = Q1; IDXO = I1; }
    else                     { lvl = 2; lb = base - r0 - r1;  X = X2; CB = C2; FLAG = F2; Q = Q2; IDXO = I2; }
    const float* E2EMU = E2A + lvl * KN;

    unsigned char f = FLAG[lb + lane];
    unsigned long long mask = __ballot(f != 0);
    while (mask) {
      int bit = __ffsll((long long)mask) - 1;
      mask &= mask - 1;
      const int r = lb + bit;
      const float* xr = X + (size_t)r * DD;
      const float xx = emu_sq_pairwise384(xr);

      float best = 1e30f; int bidx = 0x7fffffff;
#pragma unroll
      for (int t = 0; t < 4; ++t) {
        int k = lane * 4 + t;
        const float* ck = CB + (size_t)k * DD;
        float E = emu_dot384_np(xr, ck);
        float s = __fadd_rn(__fsub_rn(xx, __fmul_rn(2.0f, E)), E2EMU[k]);
        if (s < best || (s == best && k < bidx)) { best = s; bidx = k; }
      }
#pragma unroll
      for (int m = 1; m < 64; m <<= 1) {
        float ob = __shfl_xor(best, m);
        int   oi = __shfl_xor(bidx, m);
        if (ob < best || (ob == best && oi < bidx)) { best = ob; bidx = oi; }
      }

      const int old = (int)IDXO[r];
      if (bidx != old) {
        const float* cn = CB + (size_t)bidx * DD;
        const float* co = CB + (size_t)old * DD;
        double dl = 0.0;
        for (int d = lane; d < DD; d += 64) {
          float xv = xr[d];
          float qn = cn[d], qo = co[d];
          Q[(size_t)r * DD + d] = qn;
          double en = (double)qn - (double)xv;
          double eo = (double)qo - (double)xv;
          dl += en * en - eo * eo;
        }
#pragma unroll
        for (int m = 1; m < 64; m <<= 1) dl += __shfl_xor(dl, m);
        if (lane == 0) {
          atomicAdd(DELTA + lvl, dl);
          IDXO[r] = (float)bidx;
        }
      }
    }
  }
}

// ---------------- loss finalize ----------------
__global__ void finalize_kernel(const double* __restrict__ p0, int n0, double w0,
                                const double* __restrict__ p1, int n1, double w1,
                                const double* __restrict__ p2, int n2, double w2,
                                const double* __restrict__ delta,
                                float* __restrict__ out) {
  __shared__ double red[4];
  int tid = threadIdx.x;
  double s0 = 0.0, s1 = 0.0, s2 = 0.0;
  for (int i = tid; i < n0; i += 256) s0 += p0[i];
  for (int i = tid; i < n1; i += 256) s1 += p1[i];
  for (int i = tid; i < n2; i += 256) s2 += p2[i];
  double v = s0 * w0 + s1 * w1 + s2 * w2;
#pragma unroll
  for (int m = 1; m < 64; m <<= 1) v += __shfl_xor(v, m);
  if ((tid & 63) == 0) red[tid >> 6] = v;
  __syncthreads();
  if (tid == 0)
    out[0] = (float)(red[0] + red[1] + red[2] + red[3]
                     + delta[0] * w0 + delta[1] * w1 + delta[2] * w2);
}

extern "C" void kernel_launch(void* const* d_in, const int* in_sizes, int n_in,
                              void* d_out, int out_size, void* d_ws, size_t ws_size,
                              hipStream_t stream) {
  const float* l0  = (const float*)d_in[0];
  const float* l1  = (const float*)d_in[1];
  const float* l2  = (const float*)d_in[2];
  const float* cb0 = (const float*)d_in[3];
  const float* cb1 = (const float*)d_in[4];
  const float* cb2 = (const float*)d_in[5];

  const size_t n_q0 = (size_t)in_sizes[0];
  const size_t n_q1 = (size_t)in_sizes[1];
  const size_t n_q2 = (size_t)in_sizes[2];
  const int r0 = (int)(n_q0 / DD);   // 65536
  const int r1 = (int)(n_q1 / DD);   // 262144
  const int r2 = (int)(n_q2 / DD);   // 262144

  float* out   = (float*)d_out;
  float* q0    = out;
  float* q1    = q0 + n_q0;
  float* q2    = q1 + n_q1;
  float* lossp = q2 + n_q2;
  float* idx0  = lossp + 1;
  float* idx1  = idx0 + r0;
  float* idx2  = idx1 + r1;

  // ws layout
  float*  e2    = (float*)d_ws;                          // 3*256 f32
  double* part  = (double*)((char*)d_ws + 4096);         // 9216 doubles
  double* delta = (double*)((char*)d_ws + 4096 + 73728);
  unsigned char* flag0 = (unsigned char*)d_ws + 4096 + 73728 + 1024;
  unsigned char* flag1 = flag0 + r0;
  unsigned char* flag2 = flag1 + r1;
  short* cbf0 = (short*)((char*)d_ws + (1 << 20));       // 3 x 384 KiB

  const int nb0 = r0 / TM, nb1 = r1 / TM, nb2 = r2 / TM;  // 1024/4096/4096
  double* p0 = part;
  double* p1 = p0 + nb0;
  double* p2 = p1 + nb1;

  prep_kernel<<<147, 256, 0, stream>>>(cb0, cb1, cb2, e2, delta, cbf0);

  vq_main<<<nb0 + nb1 + nb2, 256, 0, stream>>>(
      l0, l1, l2, cb0, cb1, cb2, cbf0, e2,
      q0, idx0, flag0, part, nb0, nb1);

  vq_refine<<<512, 256, 0, stream>>>(l0, l1, l2, cb0, cb1, cb2, e2,
                                     flag0, flag1, flag2, r0, r1, r2,
                                     q0, q1, q2, idx0, idx1, idx2, delta);

  const double w0 = 0.05 / ((double)r0 * DD);
  const double w1 = 0.25 / ((double)r1 * DD);
  const double w2 = 0.60 / ((double)r2 * DD);
  finalize_kernel<<<1, 256, 0, stream>>>(p0, nb0, w0, p1, nb1, w1, p2, nb2, w2,
                                         delta, lossp);
}